// Round 9
// baseline (706.370 us; speedup 1.0000x reference)
//
#include <hip/hip_runtime.h>

#define NN 100000
#define NE 1600000

constexpr int F_IN = 58;
constexpr int F_H  = 16;
constexpr int KS   = 2;
constexpr int FH2  = 32;            // KS * F_H
constexpr int NPAIR = F_IN / 2;     // 29

constexpr int NB   = 391;           // buckets: col >> 8
constexpr int NBLK = 256;           // partition blocks
constexpr int EPB  = NE / NBLK;     // 6250
constexpr int SCANN = NB * NBLK;    // 100096
constexpr int SCAN_BLOCKS = (SCANN + 1023) / 1024;  // 98
constexpr int NODES_PER_BLK = 64;   // dense1: 8 groups x 8 nodes
constexpr int DENSE_BLOCKS = (NN + NODES_PER_BLK - 1) / NODES_PER_BLK;  // 1563

// blocks [0,NBLK): per-block bucket histogram (single-copy LDS atomics —
//   4-way replication measured WORSE: same-address atomics merge fine).
// blocks [NBLK,...): dense layer-1, 8 nodes/thread, x via global broadcast.
__global__ void k_hist_dense1(const int* __restrict__ col, int* __restrict__ bh,
                              const float* __restrict__ x,
                              const float* __restrict__ Wi, const float* __restrict__ Wr,
                              const float* __restrict__ b,
                              float* __restrict__ h1, float* __restrict__ r1) {
    __shared__ float swi2[NPAIR * 64];   // [pair][ko*2+q] = Wi[2p+q][ko]
    __shared__ float swr2[NPAIR * 64];
    __shared__ int hist[NB];
    int tid = threadIdx.x;

    if (blockIdx.x < NBLK) {
        int blk = blockIdx.x;
        for (int i = tid; i < NB; i += 256) hist[i] = 0;
        __syncthreads();
        int base = blk * EPB;
        for (int e = base + tid; e < base + EPB; e += 256)
            atomicAdd(&hist[col[e] >> 8], 1);
        __syncthreads();
        for (int i = tid; i < NB; i += 256)
            bh[i * NBLK + blk] = hist[i];
        return;
    }

    // pack weight pairs: swi2[p*64 + ko*2 + q] = Wi[(k*F_IN + 2p+q)*F_H + o]
    for (int t = tid; t < NPAIR * 64; t += 256) {
        int p = t >> 6, r = t & 63;
        int ko = r >> 1, q = r & 1;
        int i = p * 2 + q;
        int k = ko >> 4, o = ko & 15;
        swi2[t] = Wi[(k * F_IN + i) * F_H + o];
        swr2[t] = Wr[(k * F_IN + i) * F_H + o];
    }
    __syncthreads();
    int ko = tid & 31, g = tid >> 5;
    int n0 = (blockIdx.x - NBLK) * NODES_PER_BLK + g * 8;  // 8 nodes per thread
    float hi[8] = {0.f, 0.f, 0.f, 0.f, 0.f, 0.f, 0.f, 0.f};
    float hr[8] = {0.f, 0.f, 0.f, 0.f, 0.f, 0.f, 0.f, 0.f};
#pragma unroll
    for (int s = 0; s < 14; s++) {                 // i = 4s .. 4s+3
        float2 wiA = *(const float2*)&swi2[(s << 7) + (ko << 1)];        // pair 2s
        float2 wiB = *(const float2*)&swi2[(s << 7) + 64 + (ko << 1)];   // pair 2s+1
        float2 wrA = *(const float2*)&swr2[(s << 7) + (ko << 1)];
        float2 wrB = *(const float2*)&swr2[(s << 7) + 64 + (ko << 1)];
#pragma unroll
        for (int i = 0; i < 8; i++) {
            int n = n0 + i; if (n >= NN) n = NN - 1;        // clamp (store guarded)
            float4 xv = *(const float4*)&x[(size_t)n * F_IN + s * 4];    // broadcast
            hi[i] = fmaf(xv.x, wiA.x, hi[i]); hi[i] = fmaf(xv.y, wiA.y, hi[i]);
            hi[i] = fmaf(xv.z, wiB.x, hi[i]); hi[i] = fmaf(xv.w, wiB.y, hi[i]);
            hr[i] = fmaf(xv.x, wrA.x, hr[i]); hr[i] = fmaf(xv.y, wrA.y, hr[i]);
            hr[i] = fmaf(xv.z, wrB.x, hr[i]); hr[i] = fmaf(xv.w, wrB.y, hr[i]);
        }
    }
    {   // tail: i = 56,57 (pair 28)
        float2 wiA = *(const float2*)&swi2[(28 << 6) + (ko << 1)];
        float2 wrA = *(const float2*)&swr2[(28 << 6) + (ko << 1)];
#pragma unroll
        for (int i = 0; i < 8; i++) {
            int n = n0 + i; if (n >= NN) n = NN - 1;
            float2 xv = *(const float2*)&x[(size_t)n * F_IN + 56];
            hi[i] = fmaf(xv.x, wiA.x, hi[i]); hi[i] = fmaf(xv.y, wiA.y, hi[i]);
            hr[i] = fmaf(xv.x, wrA.x, hr[i]); hr[i] = fmaf(xv.y, wrA.y, hr[i]);
        }
    }
    float bv = b[ko];
#pragma unroll
    for (int i = 0; i < 8; i++) {
        int n = n0 + i;
        if (n < NN) {
            h1[(size_t)n * FH2 + ko] = hi[i];
            r1[(size_t)n * FH2 + ko] = hr[i] + bv;
        }
    }
}

__global__ void k_scan1(int* __restrict__ bh, int* __restrict__ bsum) {
    __shared__ int ts[256];
    int tid = threadIdx.x;
    int base = blockIdx.x * 1024 + tid * 4;
    int v0 = (base + 0 < SCANN) ? bh[base + 0] : 0;
    int v1 = (base + 1 < SCANN) ? bh[base + 1] : 0;
    int v2 = (base + 2 < SCANN) ? bh[base + 2] : 0;
    int v3 = (base + 3 < SCANN) ? bh[base + 3] : 0;
    int p0 = v0, p1 = p0 + v1, p2 = p1 + v2, p3 = p2 + v3;
    ts[tid] = p3;
    __syncthreads();
    for (int off = 1; off < 256; off <<= 1) {
        int v = (tid >= off) ? ts[tid - off] : 0;
        __syncthreads();
        ts[tid] += v;
        __syncthreads();
    }
    int prev = (tid > 0) ? ts[tid - 1] : 0;
    if (base + 0 < SCANN) bh[base + 0] = prev + p0;
    if (base + 1 < SCANN) bh[base + 1] = prev + p1;
    if (base + 2 < SCANN) bh[base + 2] = prev + p2;
    if (base + 3 < SCANN) bh[base + 3] = prev + p3;
    if (tid == 255) bsum[blockIdx.x] = ts[255];
}

__global__ void k_scan2(const int* __restrict__ bsum, int* __restrict__ boff) {
    __shared__ int s[128];
    int tid = threadIdx.x;
    s[tid] = (tid < SCAN_BLOCKS) ? bsum[tid] : 0;
    __syncthreads();
    for (int off = 1; off < 128; off <<= 1) {
        int v = (tid >= off) ? s[tid - off] : 0;
        __syncthreads();
        s[tid] += v;
        __syncthreads();
    }
    if (tid < SCAN_BLOCKS) boff[tid] = (tid > 0) ? s[tid - 1] : 0;
}

__global__ void k_scan3(int* __restrict__ bh, const int* __restrict__ boff) {
    int i = blockIdx.x * blockDim.x + threadIdx.x;
    if (i < SCANN) bh[i] += boff[i >> 10];
}

__global__ void k_bscatter(const int* __restrict__ row, const int* __restrict__ col,
                           const int* __restrict__ bh, int* __restrict__ ebuck) {
    __shared__ int cur[NB];
    int tid = threadIdx.x, blk = blockIdx.x;
    for (int i = tid; i < NB; i += 256) {
        int idx = i * NBLK + blk;
        cur[i] = (idx == 0) ? 0 : bh[idx - 1];
    }
    __syncthreads();
    int base = blk * EPB;
    for (int e = base + tid; e < base + EPB; e += 256) {
        int c = col[e];
        int pos = atomicAdd(&cur[c >> 8], 1);
        ebuck[pos] = (row[e] << 8) | (c & 255);
    }
}

// per bucket: per-col counts (2-way replicated) + scan -> inc, dis
__global__ void __launch_bounds__(256) k_bcsr_a(const int* __restrict__ bh,
                                                const int* __restrict__ ebuck,
                                                int* __restrict__ inc, float* __restrict__ dis) {
    __shared__ int cnt[514];
    __shared__ int scn[256];
    int b = blockIdx.x, tid = threadIdx.x;
    int start = (b == 0) ? 0 : bh[b * NBLK - 1];
    int end   = bh[(b + 1) * NBLK - 1];
    cnt[tid] = 0; cnt[257 + tid] = 0;
    __syncthreads();
    int c0 = (tid & 1) * 257;
    for (int j = start + tid; j < end; j += 256)
        atomicAdd(&cnt[c0 + (ebuck[j] & 255)], 1);
    __syncthreads();
    int v = cnt[tid] + cnt[257 + tid];
    scn[tid] = v;
    __syncthreads();
    for (int off = 1; off < 256; off <<= 1) {
        int t = (tid >= off) ? scn[tid - off] : 0;
        __syncthreads();
        scn[tid] += t;
        __syncthreads();
    }
    int colIdx = (b << 8) + tid;
    if (colIdx < NN) {
        inc[colIdx] = start + scn[tid];
        dis[colIdx] = (v > 0) ? rsqrtf((float)v) : 0.f;
    }
}

// per bucket: scatter packed (src, w = dis[src]*dis[col]) into CSR order
__global__ void __launch_bounds__(256) k_bcsr_b(const int* __restrict__ bh,
                                                const int* __restrict__ ebuck,
                                                const int* __restrict__ inc,
                                                const float* __restrict__ dis,
                                                int2* __restrict__ esrc8) {
    __shared__ int cur[256];
    __shared__ float sdis[256];
    int b = blockIdx.x, tid = threadIdx.x;
    int start = (b == 0) ? 0 : bh[b * NBLK - 1];
    int end   = bh[(b + 1) * NBLK - 1];
    int colIdx = (b << 8) + tid;
    cur[tid]  = (colIdx == 0) ? 0 : ((colIdx <= NN) ? inc[colIdx - 1] : 0);
    sdis[tid] = (colIdx < NN) ? dis[colIdx] : 0.f;
    __syncthreads();
    for (int j = start + tid; j < end; j += 256) {
        int e = ebuck[j];
        int c = e & 255, s = e >> 8;
        int pos = atomicAdd(&cur[c], 1);
        float w = dis[s] * sdis[c];
        esrc8[pos] = make_int2(s, __float_as_int(w));
    }
}

// layer1 gather + relu + K-mean + dense2. 8 lanes/node, float4 rows, packed edges.
__global__ void k_gather1_mid(const int* __restrict__ inc, const int2* __restrict__ esrc8,
                              const float4* __restrict__ h1, const float4* __restrict__ r1,
                              const float4* __restrict__ Wi2, const float4* __restrict__ Wr2,
                              const float* __restrict__ b2,
                              float* __restrict__ h2, float* __restrict__ r2) {
    int tid = blockIdx.x * blockDim.x + threadIdx.x;
    int n = tid >> 3, l = tid & 7;
    if (n >= NN) return;
    int js = (n == 0) ? 0 : inc[n - 1];
    int je = inc[n];
    float4 acc = r1[(size_t)n * 8 + l];
    int j = js;
    if ((j & 1) && j < je) {
        int2 e = esrc8[j];
        float w = __int_as_float(e.y);
        float4 v = h1[(size_t)e.x * 8 + l];
        acc.x = fmaf(w, v.x, acc.x); acc.y = fmaf(w, v.y, acc.y);
        acc.z = fmaf(w, v.z, acc.z); acc.w = fmaf(w, v.w, acc.w);
        j++;
    }
    for (; j + 1 < je; j += 2) {
        int4 ep = *(const int4*)&esrc8[j];
        float w0 = __int_as_float(ep.y), w1 = __int_as_float(ep.w);
        float4 v0 = h1[(size_t)ep.x * 8 + l];
        float4 v1 = h1[(size_t)ep.z * 8 + l];
        acc.x = fmaf(w0, v0.x, acc.x); acc.y = fmaf(w0, v0.y, acc.y);
        acc.z = fmaf(w0, v0.z, acc.z); acc.w = fmaf(w0, v0.w, acc.w);
        acc.x = fmaf(w1, v1.x, acc.x); acc.y = fmaf(w1, v1.y, acc.y);
        acc.z = fmaf(w1, v1.z, acc.z); acc.w = fmaf(w1, v1.w, acc.w);
    }
    if (j < je) {
        int2 e = esrc8[j];
        float w = __int_as_float(e.y);
        float4 v = h1[(size_t)e.x * 8 + l];
        acc.x = fmaf(w, v.x, acc.x); acc.y = fmaf(w, v.y, acc.y);
        acc.z = fmaf(w, v.z, acc.z); acc.w = fmaf(w, v.w, acc.w);
    }
    acc.x = fmaxf(acc.x, 0.f); acc.y = fmaxf(acc.y, 0.f);
    acc.z = fmaxf(acc.z, 0.f); acc.w = fmaxf(acc.w, 0.f);
    float4 h;
    h.x = 0.5f * (acc.x + __shfl_xor(acc.x, 4));
    h.y = 0.5f * (acc.y + __shfl_xor(acc.y, 4));
    h.z = 0.5f * (acc.z + __shfl_xor(acc.z, 4));
    h.w = 0.5f * (acc.w + __shfl_xor(acc.w, 4));
    float4 wi = Wi2[l], wr = Wr2[l];
    float p1 = h.x * wi.x + h.y * wi.y + h.z * wi.z + h.w * wi.w;
    float p2 = h.x * wr.x + h.y * wr.y + h.z * wr.z + h.w * wr.w;
    p1 += __shfl_xor(p1, 1); p1 += __shfl_xor(p1, 2);
    p2 += __shfl_xor(p2, 1); p2 += __shfl_xor(p2, 2);
    if ((l & 3) == 0) {
        int k = l >> 2;
        h2[n * 2 + k] = p1;
        r2[n * 2 + k] = p2 + b2[k];
    }
}

// layer2 gather: 8 lanes/node, edge-parallel over packed pairs
__global__ void k_gather2(const int* __restrict__ inc, const int2* __restrict__ esrc8,
                          const float* __restrict__ h2, const float* __restrict__ r2,
                          float* __restrict__ out) {
    int tid = blockIdx.x * blockDim.x + threadIdx.x;
    int n = tid >> 3, l = tid & 7;
    if (n >= NN) return;
    int js = (n == 0) ? 0 : inc[n - 1];
    int je = inc[n];
    float a0 = 0.f, a1v = 0.f;
    for (int j = js + l; j < je; j += 8) {
        int2 e = esrc8[j];
        float w = __int_as_float(e.y);
        float2 hv = *(const float2*)&h2[(size_t)e.x * 2];
        a0  = fmaf(w, hv.x, a0);
        a1v = fmaf(w, hv.y, a1v);
    }
    a0  += __shfl_xor(a0, 1);  a0  += __shfl_xor(a0, 2);  a0  += __shfl_xor(a0, 4);
    a1v += __shfl_xor(a1v, 1); a1v += __shfl_xor(a1v, 2); a1v += __shfl_xor(a1v, 4);
    if (l == 0) {
        float2 rv = *(const float2*)&r2[(size_t)n * 2];
        out[n] = 0.5f * (fmaxf(a0 + rv.x, 0.f) + fmaxf(a1v + rv.y, 0.f));
    }
}

extern "C" void kernel_launch(void* const* d_in, const int* in_sizes, int n_in,
                              void* d_out, int out_size, void* d_ws, size_t ws_size,
                              hipStream_t stream) {
    const float* x   = (const float*)d_in[0];
    const int*   ei  = (const int*)d_in[1];
    const float* Wi1 = (const float*)d_in[2];
    const float* Wr1 = (const float*)d_in[3];
    const float* b1  = (const float*)d_in[4];
    const float* Wi2 = (const float*)d_in[5];
    const float* Wr2 = (const float*)d_in[6];
    const float* b2  = (const float*)d_in[7];
    float* out = (float*)d_out;

    const int* row = ei;
    const int* col = ei + NE;

    int*   bh    = (int*)d_ws;                       // 100096
    int*   bsum  = bh + SCANN;                       // 128
    int*   boff  = bsum + 128;                       // 128
    float* dis   = (float*)(boff + 128);             // NN
    int*   inc   = (int*)(dis + NN);                 // NN
    int*   ebuck = inc + NN;                         // NE
    int2*  esrc8 = (int2*)(ebuck + NE);              // NE int2 (16B-aligned)
    float* h1    = (float*)(esrc8 + NE);             // NN*32
    float* r1    = h1 + (size_t)NN * FH2;            // NN*32
    float* h2    = r1 + (size_t)NN * FH2;            // NN*2
    float* r2    = h2 + (size_t)NN * KS;             // NN*2

    const int B = 256;
    k_hist_dense1<<<NBLK + DENSE_BLOCKS, B, 0, stream>>>(col, bh, x, Wi1, Wr1, b1, h1, r1);
    k_scan1<<<SCAN_BLOCKS, B, 0, stream>>>(bh, bsum);
    k_scan2<<<1, 128, 0, stream>>>(bsum, boff);
    k_scan3<<<(SCANN + B - 1) / B, B, 0, stream>>>(bh, boff);
    k_bscatter<<<NBLK, B, 0, stream>>>(row, col, bh, ebuck);
    k_bcsr_a<<<NB, B, 0, stream>>>(bh, ebuck, inc, dis);
    k_bcsr_b<<<NB, B, 0, stream>>>(bh, ebuck, inc, dis, esrc8);
    k_gather1_mid<<<(NN * 8 + B - 1) / B, B, 0, stream>>>(inc, esrc8,
        (const float4*)h1, (const float4*)r1, (const float4*)Wi2, (const float4*)Wr2,
        b2, h2, r2);
    k_gather2<<<(NN * 8 + B - 1) / B, B, 0, stream>>>(inc, esrc8, h2, r2, out);
}

// Round 10
// 495.160 us; speedup vs baseline: 1.4265x; 1.4265x over previous
//
#include <hip/hip_runtime.h>

#define NN 100000
#define NE 1600000

constexpr int F_IN = 58;
constexpr int F_H  = 16;
constexpr int KS   = 2;
constexpr int FH2  = 32;            // KS * F_H
constexpr int NPAIR = F_IN / 2;     // 29
constexpr int SXP = 60;             // padded x row stride (240B, 16B-aligned)

constexpr int NB   = 391;           // buckets: col >> 8
constexpr int NBLK = 256;           // partition blocks
constexpr int EPB  = NE / NBLK;     // 6250
constexpr int SCANN = NB * NBLK;    // 100096
constexpr int SCAN_BLOCKS = (SCANN + 1023) / 1024;  // 98
constexpr int NODES_PER_BLK = 64;   // dense1: 8 groups x 8 nodes/thread
constexpr int DENSE_BLOCKS = (NN + NODES_PER_BLK - 1) / NODES_PER_BLK;  // 1563

// blocks [0,NBLK): per-block bucket histogram (single-copy LDS atomics).
// blocks [NBLK,...): dense layer-1: x staged in LDS, 8 nodes/thread.
__global__ void k_hist_dense1(const int* __restrict__ col, int* __restrict__ bh,
                              const float* __restrict__ x,
                              const float* __restrict__ Wi, const float* __restrict__ Wr,
                              const float* __restrict__ b,
                              float* __restrict__ h1, float* __restrict__ r1) {
    __shared__ float swi2[NPAIR * 64];     // [pair][ko*2+q] = Wi[2p+q][ko]
    __shared__ float swr2[NPAIR * 64];
    __shared__ float sx[NODES_PER_BLK * SXP];
    __shared__ int hist[NB];
    int tid = threadIdx.x;

    if (blockIdx.x < NBLK) {
        int blk = blockIdx.x;
        for (int i = tid; i < NB; i += 256) hist[i] = 0;
        __syncthreads();
        int base = blk * EPB;
        for (int e = base + tid; e < base + EPB; e += 256)
            atomicAdd(&hist[col[e] >> 8], 1);
        __syncthreads();
        for (int i = tid; i < NB; i += 256)
            bh[i * NBLK + blk] = hist[i];
        return;
    }

    // pack weight pairs: swi2[p*64 + ko*2 + q] = Wi[(k*F_IN + 2p+q)*F_H + o]
    for (int t = tid; t < NPAIR * 64; t += 256) {
        int p = t >> 6, r = t & 63;
        int ko = r >> 1, q = r & 1;
        int i = p * 2 + q;
        int k = ko >> 4, o = ko & 15;
        swi2[t] = Wi[(k * F_IN + i) * F_H + o];
        swr2[t] = Wr[(k * F_IN + i) * F_H + o];
    }
    // stage 64 node rows of x (coalesced global read)
    int nodeBase = (blockIdx.x - NBLK) * NODES_PER_BLK;
    for (int t = tid; t < NODES_PER_BLK * F_IN; t += 256) {
        int ln = t / F_IN, i = t - ln * F_IN;
        int n = nodeBase + ln;
        sx[ln * SXP + i] = (n < NN) ? x[(size_t)n * F_IN + i] : 0.f;
    }
    __syncthreads();

    int ko = tid & 31, g = tid >> 5;
    int l0 = g * 8;                       // this thread's 8 local nodes
    float hi[8] = {0,0,0,0,0,0,0,0};
    float hr[8] = {0,0,0,0,0,0,0,0};
#pragma unroll
    for (int s = 0; s < 14; s++) {        // i = 4s .. 4s+3  (pairs 2s, 2s+1)
        float2 wiA = *(const float2*)&swi2[(s << 7) + (ko << 1)];
        float2 wiB = *(const float2*)&swi2[(s << 7) + 64 + (ko << 1)];
        float2 wrA = *(const float2*)&swr2[(s << 7) + (ko << 1)];
        float2 wrB = *(const float2*)&swr2[(s << 7) + 64 + (ko << 1)];
#pragma unroll
        for (int i = 0; i < 8; i++) {
            float4 xv = *(const float4*)&sx[(l0 + i) * SXP + s * 4];  // LDS broadcast
            hi[i] = fmaf(xv.x, wiA.x, hi[i]); hi[i] = fmaf(xv.y, wiA.y, hi[i]);
            hi[i] = fmaf(xv.z, wiB.x, hi[i]); hi[i] = fmaf(xv.w, wiB.y, hi[i]);
            hr[i] = fmaf(xv.x, wrA.x, hr[i]); hr[i] = fmaf(xv.y, wrA.y, hr[i]);
            hr[i] = fmaf(xv.z, wrB.x, hr[i]); hr[i] = fmaf(xv.w, wrB.y, hr[i]);
        }
    }
    {   // tail: i = 56,57 (pair 28)
        float2 wiA = *(const float2*)&swi2[(28 << 6) + (ko << 1)];
        float2 wrA = *(const float2*)&swr2[(28 << 6) + (ko << 1)];
#pragma unroll
        for (int i = 0; i < 8; i++) {
            float2 xv = *(const float2*)&sx[(l0 + i) * SXP + 56];
            hi[i] = fmaf(xv.x, wiA.x, hi[i]); hi[i] = fmaf(xv.y, wiA.y, hi[i]);
            hr[i] = fmaf(xv.x, wrA.x, hr[i]); hr[i] = fmaf(xv.y, wrA.y, hr[i]);
        }
    }
    float bv = b[ko];
#pragma unroll
    for (int i = 0; i < 8; i++) {
        int n = nodeBase + l0 + i;
        if (n < NN) {
            h1[(size_t)n * FH2 + ko] = hi[i];
            r1[(size_t)n * FH2 + ko] = hr[i] + bv;
        }
    }
}

__global__ void k_scan1(int* __restrict__ bh, int* __restrict__ bsum) {
    __shared__ int ts[256];
    int tid = threadIdx.x;
    int base = blockIdx.x * 1024 + tid * 4;
    int v0 = (base + 0 < SCANN) ? bh[base + 0] : 0;
    int v1 = (base + 1 < SCANN) ? bh[base + 1] : 0;
    int v2 = (base + 2 < SCANN) ? bh[base + 2] : 0;
    int v3 = (base + 3 < SCANN) ? bh[base + 3] : 0;
    int p0 = v0, p1 = p0 + v1, p2 = p1 + v2, p3 = p2 + v3;
    ts[tid] = p3;
    __syncthreads();
    for (int off = 1; off < 256; off <<= 1) {
        int v = (tid >= off) ? ts[tid - off] : 0;
        __syncthreads();
        ts[tid] += v;
        __syncthreads();
    }
    int prev = (tid > 0) ? ts[tid - 1] : 0;
    if (base + 0 < SCANN) bh[base + 0] = prev + p0;
    if (base + 1 < SCANN) bh[base + 1] = prev + p1;
    if (base + 2 < SCANN) bh[base + 2] = prev + p2;
    if (base + 3 < SCANN) bh[base + 3] = prev + p3;
    if (tid == 255) bsum[blockIdx.x] = ts[255];
}

__global__ void k_scan2(const int* __restrict__ bsum, int* __restrict__ boff) {
    __shared__ int s[128];
    int tid = threadIdx.x;
    s[tid] = (tid < SCAN_BLOCKS) ? bsum[tid] : 0;
    __syncthreads();
    for (int off = 1; off < 128; off <<= 1) {
        int v = (tid >= off) ? s[tid - off] : 0;
        __syncthreads();
        s[tid] += v;
        __syncthreads();
    }
    if (tid < SCAN_BLOCKS) boff[tid] = (tid > 0) ? s[tid - 1] : 0;
}

__global__ void k_scan3(int* __restrict__ bh, const int* __restrict__ boff) {
    int i = blockIdx.x * blockDim.x + threadIdx.x;
    if (i < SCANN) bh[i] += boff[i >> 10];
}

__global__ void k_bscatter(const int* __restrict__ row, const int* __restrict__ col,
                           const int* __restrict__ bh, int* __restrict__ ebuck) {
    __shared__ int cur[NB];
    int tid = threadIdx.x, blk = blockIdx.x;
    for (int i = tid; i < NB; i += 256) {
        int idx = i * NBLK + blk;
        cur[i] = (idx == 0) ? 0 : bh[idx - 1];
    }
    __syncthreads();
    int base = blk * EPB;
    for (int e = base + tid; e < base + EPB; e += 256) {
        int c = col[e];
        int pos = atomicAdd(&cur[c >> 8], 1);
        ebuck[pos] = (row[e] << 8) | (c & 255);
    }
}

// per bucket: per-col counts (2-way replicated) + scan -> inc, dis
__global__ void __launch_bounds__(256) k_bcsr_a(const int* __restrict__ bh,
                                                const int* __restrict__ ebuck,
                                                int* __restrict__ inc, float* __restrict__ dis) {
    __shared__ int cnt[514];
    __shared__ int scn[256];
    int b = blockIdx.x, tid = threadIdx.x;
    int start = (b == 0) ? 0 : bh[b * NBLK - 1];
    int end   = bh[(b + 1) * NBLK - 1];
    cnt[tid] = 0; cnt[257 + tid] = 0;
    __syncthreads();
    int c0 = (tid & 1) * 257;
    for (int j = start + tid; j < end; j += 256)
        atomicAdd(&cnt[c0 + (ebuck[j] & 255)], 1);
    __syncthreads();
    int v = cnt[tid] + cnt[257 + tid];
    scn[tid] = v;
    __syncthreads();
    for (int off = 1; off < 256; off <<= 1) {
        int t = (tid >= off) ? scn[tid - off] : 0;
        __syncthreads();
        scn[tid] += t;
        __syncthreads();
    }
    int colIdx = (b << 8) + tid;
    if (colIdx < NN) {
        inc[colIdx] = start + scn[tid];
        dis[colIdx] = (v > 0) ? rsqrtf((float)v) : 0.f;
    }
}

// per bucket: scatter packed (src, w = dis[src]*dis[col]) into CSR order
__global__ void __launch_bounds__(256) k_bcsr_b(const int* __restrict__ bh,
                                                const int* __restrict__ ebuck,
                                                const int* __restrict__ inc,
                                                const float* __restrict__ dis,
                                                int2* __restrict__ esrc8) {
    __shared__ int cur[256];
    __shared__ float sdis[256];
    int b = blockIdx.x, tid = threadIdx.x;
    int start = (b == 0) ? 0 : bh[b * NBLK - 1];
    int end   = bh[(b + 1) * NBLK - 1];
    int colIdx = (b << 8) + tid;
    cur[tid]  = (colIdx == 0) ? 0 : ((colIdx <= NN) ? inc[colIdx - 1] : 0);
    sdis[tid] = (colIdx < NN) ? dis[colIdx] : 0.f;
    __syncthreads();
    for (int j = start + tid; j < end; j += 256) {
        int e = ebuck[j];
        int c = e & 255, s = e >> 8;
        int pos = atomicAdd(&cur[c], 1);
        float w = dis[s] * sdis[c];
        esrc8[pos] = make_int2(s, __float_as_int(w));
    }
}

// layer1 gather + relu + K-mean + dense2. 8 lanes/node, float4 rows, packed edges.
__global__ void k_gather1_mid(const int* __restrict__ inc, const int2* __restrict__ esrc8,
                              const float4* __restrict__ h1, const float4* __restrict__ r1,
                              const float4* __restrict__ Wi2, const float4* __restrict__ Wr2,
                              const float* __restrict__ b2,
                              float* __restrict__ h2, float* __restrict__ r2) {
    int tid = blockIdx.x * blockDim.x + threadIdx.x;
    int n = tid >> 3, l = tid & 7;
    if (n >= NN) return;
    int js = (n == 0) ? 0 : inc[n - 1];
    int je = inc[n];
    float4 acc = r1[(size_t)n * 8 + l];
    int j = js;
    if ((j & 1) && j < je) {
        int2 e = esrc8[j];
        float w = __int_as_float(e.y);
        float4 v = h1[(size_t)e.x * 8 + l];
        acc.x = fmaf(w, v.x, acc.x); acc.y = fmaf(w, v.y, acc.y);
        acc.z = fmaf(w, v.z, acc.z); acc.w = fmaf(w, v.w, acc.w);
        j++;
    }
    for (; j + 1 < je; j += 2) {
        int4 ep = *(const int4*)&esrc8[j];
        float w0 = __int_as_float(ep.y), w1 = __int_as_float(ep.w);
        float4 v0 = h1[(size_t)ep.x * 8 + l];
        float4 v1 = h1[(size_t)ep.z * 8 + l];
        acc.x = fmaf(w0, v0.x, acc.x); acc.y = fmaf(w0, v0.y, acc.y);
        acc.z = fmaf(w0, v0.z, acc.z); acc.w = fmaf(w0, v0.w, acc.w);
        acc.x = fmaf(w1, v1.x, acc.x); acc.y = fmaf(w1, v1.y, acc.y);
        acc.z = fmaf(w1, v1.z, acc.z); acc.w = fmaf(w1, v1.w, acc.w);
    }
    if (j < je) {
        int2 e = esrc8[j];
        float w = __int_as_float(e.y);
        float4 v = h1[(size_t)e.x * 8 + l];
        acc.x = fmaf(w, v.x, acc.x); acc.y = fmaf(w, v.y, acc.y);
        acc.z = fmaf(w, v.z, acc.z); acc.w = fmaf(w, v.w, acc.w);
    }
    acc.x = fmaxf(acc.x, 0.f); acc.y = fmaxf(acc.y, 0.f);
    acc.z = fmaxf(acc.z, 0.f); acc.w = fmaxf(acc.w, 0.f);
    float4 h;
    h.x = 0.5f * (acc.x + __shfl_xor(acc.x, 4));
    h.y = 0.5f * (acc.y + __shfl_xor(acc.y, 4));
    h.z = 0.5f * (acc.z + __shfl_xor(acc.z, 4));
    h.w = 0.5f * (acc.w + __shfl_xor(acc.w, 4));
    float4 wi = Wi2[l], wr = Wr2[l];
    float p1 = h.x * wi.x + h.y * wi.y + h.z * wi.z + h.w * wi.w;
    float p2 = h.x * wr.x + h.y * wr.y + h.z * wr.z + h.w * wr.w;
    p1 += __shfl_xor(p1, 1); p1 += __shfl_xor(p1, 2);
    p2 += __shfl_xor(p2, 1); p2 += __shfl_xor(p2, 2);
    if ((l & 3) == 0) {
        int k = l >> 2;
        h2[n * 2 + k] = p1;
        r2[n * 2 + k] = p2 + b2[k];
    }
}

// layer2 gather: 8 lanes/node, edge-parallel over packed pairs
__global__ void k_gather2(const int* __restrict__ inc, const int2* __restrict__ esrc8,
                          const float* __restrict__ h2, const float* __restrict__ r2,
                          float* __restrict__ out) {
    int tid = blockIdx.x * blockDim.x + threadIdx.x;
    int n = tid >> 3, l = tid & 7;
    if (n >= NN) return;
    int js = (n == 0) ? 0 : inc[n - 1];
    int je = inc[n];
    float a0 = 0.f, a1v = 0.f;
    for (int j = js + l; j < je; j += 8) {
        int2 e = esrc8[j];
        float w = __int_as_float(e.y);
        float2 hv = *(const float2*)&h2[(size_t)e.x * 2];
        a0  = fmaf(w, hv.x, a0);
        a1v = fmaf(w, hv.y, a1v);
    }
    a0  += __shfl_xor(a0, 1);  a0  += __shfl_xor(a0, 2);  a0  += __shfl_xor(a0, 4);
    a1v += __shfl_xor(a1v, 1); a1v += __shfl_xor(a1v, 2); a1v += __shfl_xor(a1v, 4);
    if (l == 0) {
        float2 rv = *(const float2*)&r2[(size_t)n * 2];
        out[n] = 0.5f * (fmaxf(a0 + rv.x, 0.f) + fmaxf(a1v + rv.y, 0.f));
    }
}

extern "C" void kernel_launch(void* const* d_in, const int* in_sizes, int n_in,
                              void* d_out, int out_size, void* d_ws, size_t ws_size,
                              hipStream_t stream) {
    const float* x   = (const float*)d_in[0];
    const int*   ei  = (const int*)d_in[1];
    const float* Wi1 = (const float*)d_in[2];
    const float* Wr1 = (const float*)d_in[3];
    const float* b1  = (const float*)d_in[4];
    const float* Wi2 = (const float*)d_in[5];
    const float* Wr2 = (const float*)d_in[6];
    const float* b2  = (const float*)d_in[7];
    float* out = (float*)d_out;

    const int* row = ei;
    const int* col = ei + NE;

    int*   bh    = (int*)d_ws;                       // 100096
    int*   bsum  = bh + SCANN;                       // 128
    int*   boff  = bsum + 128;                       // 128
    float* dis   = (float*)(boff + 128);             // NN
    int*   inc   = (int*)(dis + NN);                 // NN
    int*   ebuck = inc + NN;                         // NE
    int2*  esrc8 = (int2*)(ebuck + NE);              // NE int2 (16B-aligned)
    float* h1    = (float*)(esrc8 + NE);             // NN*32
    float* r1    = h1 + (size_t)NN * FH2;            // NN*32
    float* h2    = r1 + (size_t)NN * FH2;            // NN*2
    float* r2    = h2 + (size_t)NN * KS;             // NN*2

    const int B = 256;
    k_hist_dense1<<<NBLK + DENSE_BLOCKS, B, 0, stream>>>(col, bh, x, Wi1, Wr1, b1, h1, r1);
    k_scan1<<<SCAN_BLOCKS, B, 0, stream>>>(bh, bsum);
    k_scan2<<<1, 128, 0, stream>>>(bsum, boff);
    k_scan3<<<(SCANN + B - 1) / B, B, 0, stream>>>(bh, boff);
    k_bscatter<<<NBLK, B, 0, stream>>>(row, col, bh, ebuck);
    k_bcsr_a<<<NB, B, 0, stream>>>(bh, ebuck, inc, dis);
    k_bcsr_b<<<NB, B, 0, stream>>>(bh, ebuck, inc, dis, esrc8);
    k_gather1_mid<<<(NN * 8 + B - 1) / B, B, 0, stream>>>(inc, esrc8,
        (const float4*)h1, (const float4*)r1, (const float4*)Wi2, (const float4*)Wr2,
        b2, h2, r2);
    k_gather2<<<(NN * 8 + B - 1) / B, B, 0, stream>>>(inc, esrc8, h2, r2, out);
}

// Round 11
// 386.456 us; speedup vs baseline: 1.8278x; 1.2813x over previous
//
#include <hip/hip_runtime.h>

#define NN 100000
#define NE 1600000

constexpr int F_IN = 58;
constexpr int F_H  = 16;
constexpr int KS   = 2;
constexpr int FH2  = 32;            // KS * F_H
constexpr int NPAIR = F_IN / 2;     // 29
constexpr int SXP = 60;             // padded x row stride

constexpr int NB   = 391;           // buckets: col >> 8
constexpr int NBLK = 256;           // partition blocks
constexpr int EPB  = NE / NBLK;     // 6250
constexpr int SCANN = NB * NBLK;    // 100096
constexpr int SCAN_BLOCKS = (SCANN + 1023) / 1024;  // 98
constexpr int NODES_PER_BLK = 32;   // dense1: 8 groups x 4 nodes/thread
constexpr int DENSE_BLOCKS = (NN + NODES_PER_BLK - 1) / NODES_PER_BLK;  // 3125

// blocks [0,NBLK): per-block bucket histogram (single-copy LDS atomics).
// blocks [NBLK,...): dense1: x LDS-staged, 4 nodes/thread, NAMED scalar accs
// (register arrays spilled to scratch in R9/R10 -> 700MB HBM traffic; never again).
__global__ void k_hist_dense1(const int* __restrict__ col, int* __restrict__ bh,
                              const float* __restrict__ x,
                              const float* __restrict__ Wi, const float* __restrict__ Wr,
                              const float* __restrict__ b,
                              float* __restrict__ h1, float* __restrict__ r1) {
    __shared__ float swi2[NPAIR * 64];     // [pair][ko*2+q] = Wi[2p+q][ko]
    __shared__ float swr2[NPAIR * 64];
    __shared__ float sx[NODES_PER_BLK * SXP];
    __shared__ int hist[NB];
    int tid = threadIdx.x;

    if (blockIdx.x < NBLK) {
        int blk = blockIdx.x;
        for (int i = tid; i < NB; i += 256) hist[i] = 0;
        __syncthreads();
        int base = blk * EPB;
        for (int e = base + tid; e < base + EPB; e += 256)
            atomicAdd(&hist[col[e] >> 8], 1);
        __syncthreads();
        for (int i = tid; i < NB; i += 256)
            bh[i * NBLK + blk] = hist[i];
        return;
    }

    // pack weight pairs: swi2[p*64 + ko*2 + q] = Wi[(k*F_IN + 2p+q)*F_H + o]
    for (int t = tid; t < NPAIR * 64; t += 256) {
        int p = t >> 6, r = t & 63;
        int ko = r >> 1, q = r & 1;
        int i = p * 2 + q;
        int k = ko >> 4, o = ko & 15;
        swi2[t] = Wi[(k * F_IN + i) * F_H + o];
        swr2[t] = Wr[(k * F_IN + i) * F_H + o];
    }
    // stage 32 node rows of x (coalesced)
    int nodeBase = (blockIdx.x - NBLK) * NODES_PER_BLK;
    for (int t = tid; t < NODES_PER_BLK * F_IN; t += 256) {
        int ln = t / F_IN, i = t - ln * F_IN;
        int n = nodeBase + ln;
        sx[ln * SXP + i] = (n < NN) ? x[(size_t)n * F_IN + i] : 0.f;
    }
    __syncthreads();

    int ko = tid & 31, g = tid >> 5;
    int l0 = g * 4;                       // this thread's 4 local nodes
    float hi0 = 0.f, hi1 = 0.f, hi2 = 0.f, hi3 = 0.f;
    float hr0 = 0.f, hr1 = 0.f, hr2 = 0.f, hr3 = 0.f;
#pragma unroll
    for (int s = 0; s < 14; s++) {        // i = 4s..4s+3 (pairs 2s, 2s+1)
        float2 wiA = *(const float2*)&swi2[(s << 7) + (ko << 1)];
        float2 wiB = *(const float2*)&swi2[(s << 7) + 64 + (ko << 1)];
        float2 wrA = *(const float2*)&swr2[(s << 7) + (ko << 1)];
        float2 wrB = *(const float2*)&swr2[(s << 7) + 64 + (ko << 1)];
#define DSTEP(ii) { \
        float4 xv = *(const float4*)&sx[(l0 + ii) * SXP + s * 4]; \
        hi##ii = fmaf(xv.x, wiA.x, hi##ii); hi##ii = fmaf(xv.y, wiA.y, hi##ii); \
        hi##ii = fmaf(xv.z, wiB.x, hi##ii); hi##ii = fmaf(xv.w, wiB.y, hi##ii); \
        hr##ii = fmaf(xv.x, wrA.x, hr##ii); hr##ii = fmaf(xv.y, wrA.y, hr##ii); \
        hr##ii = fmaf(xv.z, wrB.x, hr##ii); hr##ii = fmaf(xv.w, wrB.y, hr##ii); }
        DSTEP(0) DSTEP(1) DSTEP(2) DSTEP(3)
#undef DSTEP
    }
    {   // tail: i = 56,57 (pair 28)
        float2 wiA = *(const float2*)&swi2[(28 << 6) + (ko << 1)];
        float2 wrA = *(const float2*)&swr2[(28 << 6) + (ko << 1)];
#define TSTEP(ii) { \
        float2 xv = *(const float2*)&sx[(l0 + ii) * SXP + 56]; \
        hi##ii = fmaf(xv.x, wiA.x, hi##ii); hi##ii = fmaf(xv.y, wiA.y, hi##ii); \
        hr##ii = fmaf(xv.x, wrA.x, hr##ii); hr##ii = fmaf(xv.y, wrA.y, hr##ii); }
        TSTEP(0) TSTEP(1) TSTEP(2) TSTEP(3)
#undef TSTEP
    }
    float bv = b[ko];
    int n0 = nodeBase + l0;
#define WSTEP(ii) if (n0 + ii < NN) { \
        h1[(size_t)(n0 + ii) * FH2 + ko] = hi##ii; \
        r1[(size_t)(n0 + ii) * FH2 + ko] = hr##ii + bv; }
    WSTEP(0) WSTEP(1) WSTEP(2) WSTEP(3)
#undef WSTEP
}

__global__ void k_scan1(int* __restrict__ bh, int* __restrict__ bsum) {
    __shared__ int ts[256];
    int tid = threadIdx.x;
    int base = blockIdx.x * 1024 + tid * 4;
    int v0 = (base + 0 < SCANN) ? bh[base + 0] : 0;
    int v1 = (base + 1 < SCANN) ? bh[base + 1] : 0;
    int v2 = (base + 2 < SCANN) ? bh[base + 2] : 0;
    int v3 = (base + 3 < SCANN) ? bh[base + 3] : 0;
    int p0 = v0, p1 = p0 + v1, p2 = p1 + v2, p3 = p2 + v3;
    ts[tid] = p3;
    __syncthreads();
    for (int off = 1; off < 256; off <<= 1) {
        int v = (tid >= off) ? ts[tid - off] : 0;
        __syncthreads();
        ts[tid] += v;
        __syncthreads();
    }
    int prev = (tid > 0) ? ts[tid - 1] : 0;
    if (base + 0 < SCANN) bh[base + 0] = prev + p0;
    if (base + 1 < SCANN) bh[base + 1] = prev + p1;
    if (base + 2 < SCANN) bh[base + 2] = prev + p2;
    if (base + 3 < SCANN) bh[base + 3] = prev + p3;
    if (tid == 255) bsum[blockIdx.x] = ts[255];
}

__global__ void k_scan2(const int* __restrict__ bsum, int* __restrict__ boff) {
    __shared__ int s[128];
    int tid = threadIdx.x;
    s[tid] = (tid < SCAN_BLOCKS) ? bsum[tid] : 0;
    __syncthreads();
    for (int off = 1; off < 128; off <<= 1) {
        int v = (tid >= off) ? s[tid - off] : 0;
        __syncthreads();
        s[tid] += v;
        __syncthreads();
    }
    if (tid < SCAN_BLOCKS) boff[tid] = (tid > 0) ? s[tid - 1] : 0;
}

__global__ void k_scan3(int* __restrict__ bh, const int* __restrict__ boff) {
    int i = blockIdx.x * blockDim.x + threadIdx.x;
    if (i < SCANN) bh[i] += boff[i >> 10];
}

__global__ void k_bscatter(const int* __restrict__ row, const int* __restrict__ col,
                           const int* __restrict__ bh, int* __restrict__ ebuck) {
    __shared__ int cur[NB];
    int tid = threadIdx.x, blk = blockIdx.x;
    for (int i = tid; i < NB; i += 256) {
        int idx = i * NBLK + blk;
        cur[i] = (idx == 0) ? 0 : bh[idx - 1];
    }
    __syncthreads();
    int base = blk * EPB;
    for (int e = base + tid; e < base + EPB; e += 256) {
        int c = col[e];
        int pos = atomicAdd(&cur[c >> 8], 1);
        ebuck[pos] = (row[e] << 8) | (c & 255);
    }
}

// per bucket: per-col counts (2-way replicated) + scan -> inc, dis
__global__ void __launch_bounds__(256) k_bcsr_a(const int* __restrict__ bh,
                                                const int* __restrict__ ebuck,
                                                int* __restrict__ inc, float* __restrict__ dis) {
    __shared__ int cnt[514];
    __shared__ int scn[256];
    int b = blockIdx.x, tid = threadIdx.x;
    int start = (b == 0) ? 0 : bh[b * NBLK - 1];
    int end   = bh[(b + 1) * NBLK - 1];
    cnt[tid] = 0; cnt[257 + tid] = 0;
    __syncthreads();
    int c0 = (tid & 1) * 257;
    for (int j = start + tid; j < end; j += 256)
        atomicAdd(&cnt[c0 + (ebuck[j] & 255)], 1);
    __syncthreads();
    int v = cnt[tid] + cnt[257 + tid];
    scn[tid] = v;
    __syncthreads();
    for (int off = 1; off < 256; off <<= 1) {
        int t = (tid >= off) ? scn[tid - off] : 0;
        __syncthreads();
        scn[tid] += t;
        __syncthreads();
    }
    int colIdx = (b << 8) + tid;
    if (colIdx < NN) {
        inc[colIdx] = start + scn[tid];
        dis[colIdx] = (v > 0) ? rsqrtf((float)v) : 0.f;
    }
}

// per bucket: scatter packed (src, w = dis[src]*dis[col]) into CSR order
__global__ void __launch_bounds__(256) k_bcsr_b(const int* __restrict__ bh,
                                                const int* __restrict__ ebuck,
                                                const int* __restrict__ inc,
                                                const float* __restrict__ dis,
                                                int2* __restrict__ esrc8) {
    __shared__ int cur[256];
    __shared__ float sdis[256];
    int b = blockIdx.x, tid = threadIdx.x;
    int start = (b == 0) ? 0 : bh[b * NBLK - 1];
    int end   = bh[(b + 1) * NBLK - 1];
    int colIdx = (b << 8) + tid;
    cur[tid]  = (colIdx == 0) ? 0 : ((colIdx <= NN) ? inc[colIdx - 1] : 0);
    sdis[tid] = (colIdx < NN) ? dis[colIdx] : 0.f;
    __syncthreads();
    for (int j = start + tid; j < end; j += 256) {
        int e = ebuck[j];
        int c = e & 255, s = e >> 8;
        int pos = atomicAdd(&cur[c], 1);
        float w = dis[s] * sdis[c];
        esrc8[pos] = make_int2(s, __float_as_int(w));
    }
}

// layer1 gather + relu + K-mean + dense2. 8 lanes/node, float4 rows, packed edges.
__global__ void k_gather1_mid(const int* __restrict__ inc, const int2* __restrict__ esrc8,
                              const float4* __restrict__ h1, const float4* __restrict__ r1,
                              const float4* __restrict__ Wi2, const float4* __restrict__ Wr2,
                              const float* __restrict__ b2,
                              float* __restrict__ h2, float* __restrict__ r2) {
    int tid = blockIdx.x * blockDim.x + threadIdx.x;
    int n = tid >> 3, l = tid & 7;
    if (n >= NN) return;
    int js = (n == 0) ? 0 : inc[n - 1];
    int je = inc[n];
    float4 acc = r1[(size_t)n * 8 + l];
    int j = js;
    if ((j & 1) && j < je) {
        int2 e = esrc8[j];
        float w = __int_as_float(e.y);
        float4 v = h1[(size_t)e.x * 8 + l];
        acc.x = fmaf(w, v.x, acc.x); acc.y = fmaf(w, v.y, acc.y);
        acc.z = fmaf(w, v.z, acc.z); acc.w = fmaf(w, v.w, acc.w);
        j++;
    }
    for (; j + 1 < je; j += 2) {
        int4 ep = *(const int4*)&esrc8[j];
        float w0 = __int_as_float(ep.y), w1 = __int_as_float(ep.w);
        float4 v0 = h1[(size_t)ep.x * 8 + l];
        float4 v1 = h1[(size_t)ep.z * 8 + l];
        acc.x = fmaf(w0, v0.x, acc.x); acc.y = fmaf(w0, v0.y, acc.y);
        acc.z = fmaf(w0, v0.z, acc.z); acc.w = fmaf(w0, v0.w, acc.w);
        acc.x = fmaf(w1, v1.x, acc.x); acc.y = fmaf(w1, v1.y, acc.y);
        acc.z = fmaf(w1, v1.z, acc.z); acc.w = fmaf(w1, v1.w, acc.w);
    }
    if (j < je) {
        int2 e = esrc8[j];
        float w = __int_as_float(e.y);
        float4 v = h1[(size_t)e.x * 8 + l];
        acc.x = fmaf(w, v.x, acc.x); acc.y = fmaf(w, v.y, acc.y);
        acc.z = fmaf(w, v.z, acc.z); acc.w = fmaf(w, v.w, acc.w);
    }
    acc.x = fmaxf(acc.x, 0.f); acc.y = fmaxf(acc.y, 0.f);
    acc.z = fmaxf(acc.z, 0.f); acc.w = fmaxf(acc.w, 0.f);
    float4 h;
    h.x = 0.5f * (acc.x + __shfl_xor(acc.x, 4));
    h.y = 0.5f * (acc.y + __shfl_xor(acc.y, 4));
    h.z = 0.5f * (acc.z + __shfl_xor(acc.z, 4));
    h.w = 0.5f * (acc.w + __shfl_xor(acc.w, 4));
    float4 wi = Wi2[l], wr = Wr2[l];
    float p1 = h.x * wi.x + h.y * wi.y + h.z * wi.z + h.w * wi.w;
    float p2 = h.x * wr.x + h.y * wr.y + h.z * wr.z + h.w * wr.w;
    p1 += __shfl_xor(p1, 1); p1 += __shfl_xor(p1, 2);
    p2 += __shfl_xor(p2, 1); p2 += __shfl_xor(p2, 2);
    if ((l & 3) == 0) {
        int k = l >> 2;
        h2[n * 2 + k] = p1;
        r2[n * 2 + k] = p2 + b2[k];
    }
}

// layer2 gather: 8 lanes/node, edge-parallel over packed pairs
__global__ void k_gather2(const int* __restrict__ inc, const int2* __restrict__ esrc8,
                          const float* __restrict__ h2, const float* __restrict__ r2,
                          float* __restrict__ out) {
    int tid = blockIdx.x * blockDim.x + threadIdx.x;
    int n = tid >> 3, l = tid & 7;
    if (n >= NN) return;
    int js = (n == 0) ? 0 : inc[n - 1];
    int je = inc[n];
    float a0 = 0.f, a1v = 0.f;
    for (int j = js + l; j < je; j += 8) {
        int2 e = esrc8[j];
        float w = __int_as_float(e.y);
        float2 hv = *(const float2*)&h2[(size_t)e.x * 2];
        a0  = fmaf(w, hv.x, a0);
        a1v = fmaf(w, hv.y, a1v);
    }
    a0  += __shfl_xor(a0, 1);  a0  += __shfl_xor(a0, 2);  a0  += __shfl_xor(a0, 4);
    a1v += __shfl_xor(a1v, 1); a1v += __shfl_xor(a1v, 2); a1v += __shfl_xor(a1v, 4);
    if (l == 0) {
        float2 rv = *(const float2*)&r2[(size_t)n * 2];
        out[n] = 0.5f * (fmaxf(a0 + rv.x, 0.f) + fmaxf(a1v + rv.y, 0.f));
    }
}

extern "C" void kernel_launch(void* const* d_in, const int* in_sizes, int n_in,
                              void* d_out, int out_size, void* d_ws, size_t ws_size,
                              hipStream_t stream) {
    const float* x   = (const float*)d_in[0];
    const int*   ei  = (const int*)d_in[1];
    const float* Wi1 = (const float*)d_in[2];
    const float* Wr1 = (const float*)d_in[3];
    const float* b1  = (const float*)d_in[4];
    const float* Wi2 = (const float*)d_in[5];
    const float* Wr2 = (const float*)d_in[6];
    const float* b2  = (const float*)d_in[7];
    float* out = (float*)d_out;

    const int* row = ei;
    const int* col = ei + NE;

    int*   bh    = (int*)d_ws;                       // 100096
    int*   bsum  = bh + SCANN;                       // 128
    int*   boff  = bsum + 128;                       // 128
    float* dis   = (float*)(boff + 128);             // NN
    int*   inc   = (int*)(dis + NN);                 // NN
    int*   ebuck = inc + NN;                         // NE
    int2*  esrc8 = (int2*)(ebuck + NE);              // NE int2 (16B-aligned)
    float* h1    = (float*)(esrc8 + NE);             // NN*32
    float* r1    = h1 + (size_t)NN * FH2;            // NN*32
    float* h2    = r1 + (size_t)NN * FH2;            // NN*2
    float* r2    = h2 + (size_t)NN * KS;             // NN*2

    const int B = 256;
    k_hist_dense1<<<NBLK + DENSE_BLOCKS, B, 0, stream>>>(col, bh, x, Wi1, Wr1, b1, h1, r1);
    k_scan1<<<SCAN_BLOCKS, B, 0, stream>>>(bh, bsum);
    k_scan2<<<1, 128, 0, stream>>>(bsum, boff);
    k_scan3<<<(SCANN + B - 1) / B, B, 0, stream>>>(bh, boff);
    k_bscatter<<<NBLK, B, 0, stream>>>(row, col, bh, ebuck);
    k_bcsr_a<<<NB, B, 0, stream>>>(bh, ebuck, inc, dis);
    k_bcsr_b<<<NB, B, 0, stream>>>(bh, ebuck, inc, dis, esrc8);
    k_gather1_mid<<<(NN * 8 + B - 1) / B, B, 0, stream>>>(inc, esrc8,
        (const float4*)h1, (const float4*)r1, (const float4*)Wi2, (const float4*)Wr2,
        b2, h2, r2);
    k_gather2<<<(NN * 8 + B - 1) / B, B, 0, stream>>>(inc, esrc8, h2, r2, out);
}

// Round 12
// 141.114 us; speedup vs baseline: 5.0057x; 2.7386x over previous
//
#include <hip/hip_runtime.h>

#define NN 100000
#define NE 1600000

constexpr int F_IN = 58;
constexpr int F_H  = 16;
constexpr int KS   = 2;
constexpr int FH2  = 32;            // KS * F_H
constexpr int NODES_PER_BLK = 8;
constexpr int SXP = 60;             // padded x-row stride
constexpr int NPAIR = F_IN / 2;     // 29

constexpr int NB   = 391;           // buckets: col >> 8
constexpr int NBLK = 256;           // partition blocks
constexpr int EPB  = NE / NBLK;     // 6250
constexpr int SCANN = NB * NBLK;    // 100096
constexpr int SCAN_BLOCKS = (SCANN + 1023) / 1024;  // 98
constexpr int DENSE_BLOCKS = (NN + NODES_PER_BLK - 1) / NODES_PER_BLK;  // 12500

// blocks [0,NBLK): per-block bucket histogram — SINGLE-copy LDS atomics
//   (measured: 127K conflicts vs 214K for 4-replica; same-address LDS atomics merge).
// blocks [NBLK,...): dense layer-1 — 1 node/thread (multi-node/thread variants
//   all triggered VGPR=64 + ~1GB scratch traffic; do not revisit), paired-b64
//   weight reads (2-way bank alias = free), x staged in LDS.
__global__ void k_hist_dense1(const int* __restrict__ col, int* __restrict__ bh,
                              const float* __restrict__ x,
                              const float* __restrict__ Wi, const float* __restrict__ Wr,
                              const float* __restrict__ b,
                              float* __restrict__ h1, float* __restrict__ r1) {
    __shared__ float swi2[NPAIR * 64];   // [pair][ko*2+q] = Wi[2p+q][ko]
    __shared__ float swr2[NPAIR * 64];
    __shared__ float sx[NODES_PER_BLK * SXP];
    __shared__ int hist[NB];
    int tid = threadIdx.x;

    if (blockIdx.x < NBLK) {
        int blk = blockIdx.x;
        for (int i = tid; i < NB; i += 256) hist[i] = 0;
        __syncthreads();
        int base = blk * EPB;
        for (int e = base + tid; e < base + EPB; e += 256)
            atomicAdd(&hist[col[e] >> 8], 1);
        __syncthreads();
        for (int i = tid; i < NB; i += 256)
            bh[i * NBLK + blk] = hist[i];
        return;
    }

    // pack weight pairs: swi2[p*64 + ko*2 + q] = Wi[(k*F_IN + 2p+q)*F_H + o]
    for (int t = tid; t < NPAIR * 64; t += 256) {
        int p = t >> 6, r = t & 63;
        int ko = r >> 1, q = r & 1;
        int i = p * 2 + q;
        int k = ko >> 4, o = ko & 15;
        swi2[t] = Wi[(k * F_IN + i) * F_H + o];
        swr2[t] = Wr[(k * F_IN + i) * F_H + o];
    }
    int nodeBase = (blockIdx.x - NBLK) * NODES_PER_BLK;
    for (int t = tid; t < NODES_PER_BLK * F_IN; t += 256) {
        int ln = t / F_IN, i = t - ln * F_IN;
        int n = nodeBase + ln;
        sx[ln * SXP + i] = (n < NN) ? x[(size_t)n * F_IN + i] : 0.f;
    }
    __syncthreads();
    int ln = tid >> 5, ko = tid & 31;
    int n = nodeBase + ln;
    if (n >= NN) return;
    float hi = 0.f, hr = 0.f;
#pragma unroll
    for (int p = 0; p < NPAIR; p++) {
        float2 xv = *(const float2*)&sx[ln * SXP + p * 2];
        float2 wi = *(const float2*)&swi2[(p << 6) + (ko << 1)];
        float2 wr = *(const float2*)&swr2[(p << 6) + (ko << 1)];
        hi = fmaf(xv.x, wi.x, hi);
        hi = fmaf(xv.y, wi.y, hi);
        hr = fmaf(xv.x, wr.x, hr);
        hr = fmaf(xv.y, wr.y, hr);
    }
    h1[n * FH2 + ko] = hi;
    r1[n * FH2 + ko] = hr + b[ko];
}

__global__ void k_scan1(int* __restrict__ bh, int* __restrict__ bsum) {
    __shared__ int ts[256];
    int tid = threadIdx.x;
    int base = blockIdx.x * 1024 + tid * 4;
    int v0 = (base + 0 < SCANN) ? bh[base + 0] : 0;
    int v1 = (base + 1 < SCANN) ? bh[base + 1] : 0;
    int v2 = (base + 2 < SCANN) ? bh[base + 2] : 0;
    int v3 = (base + 3 < SCANN) ? bh[base + 3] : 0;
    int p0 = v0, p1 = p0 + v1, p2 = p1 + v2, p3 = p2 + v3;
    ts[tid] = p3;
    __syncthreads();
    for (int off = 1; off < 256; off <<= 1) {
        int v = (tid >= off) ? ts[tid - off] : 0;
        __syncthreads();
        ts[tid] += v;
        __syncthreads();
    }
    int prev = (tid > 0) ? ts[tid - 1] : 0;
    if (base + 0 < SCANN) bh[base + 0] = prev + p0;
    if (base + 1 < SCANN) bh[base + 1] = prev + p1;
    if (base + 2 < SCANN) bh[base + 2] = prev + p2;
    if (base + 3 < SCANN) bh[base + 3] = prev + p3;
    if (tid == 255) bsum[blockIdx.x] = ts[255];
}

__global__ void k_scan2(const int* __restrict__ bsum, int* __restrict__ boff) {
    __shared__ int s[128];
    int tid = threadIdx.x;
    s[tid] = (tid < SCAN_BLOCKS) ? bsum[tid] : 0;
    __syncthreads();
    for (int off = 1; off < 128; off <<= 1) {
        int v = (tid >= off) ? s[tid - off] : 0;
        __syncthreads();
        s[tid] += v;
        __syncthreads();
    }
    if (tid < SCAN_BLOCKS) boff[tid] = (tid > 0) ? s[tid - 1] : 0;
}

__global__ void k_scan3(int* __restrict__ bh, const int* __restrict__ boff) {
    int i = blockIdx.x * blockDim.x + threadIdx.x;
    if (i < SCANN) bh[i] += boff[i >> 10];
}

__global__ void k_bscatter(const int* __restrict__ row, const int* __restrict__ col,
                           const int* __restrict__ bh, int* __restrict__ ebuck) {
    __shared__ int cur[NB];
    int tid = threadIdx.x, blk = blockIdx.x;
    for (int i = tid; i < NB; i += 256) {
        int idx = i * NBLK + blk;
        cur[i] = (idx == 0) ? 0 : bh[idx - 1];
    }
    __syncthreads();
    int base = blk * EPB;
    for (int e = base + tid; e < base + EPB; e += 256) {
        int c = col[e];
        int pos = atomicAdd(&cur[c >> 8], 1);
        ebuck[pos] = (row[e] << 8) | (c & 255);
    }
}

// per bucket: per-col counts (2-way replicated) + scan -> inc, dis
__global__ void __launch_bounds__(256) k_bcsr_a(const int* __restrict__ bh,
                                                const int* __restrict__ ebuck,
                                                int* __restrict__ inc, float* __restrict__ dis) {
    __shared__ int cnt[514];
    __shared__ int scn[256];
    int b = blockIdx.x, tid = threadIdx.x;
    int start = (b == 0) ? 0 : bh[b * NBLK - 1];
    int end   = bh[(b + 1) * NBLK - 1];
    cnt[tid] = 0; cnt[257 + tid] = 0;
    __syncthreads();
    int c0 = (tid & 1) * 257;
    for (int j = start + tid; j < end; j += 256)
        atomicAdd(&cnt[c0 + (ebuck[j] & 255)], 1);
    __syncthreads();
    int v = cnt[tid] + cnt[257 + tid];
    scn[tid] = v;
    __syncthreads();
    for (int off = 1; off < 256; off <<= 1) {
        int t = (tid >= off) ? scn[tid - off] : 0;
        __syncthreads();
        scn[tid] += t;
        __syncthreads();
    }
    int colIdx = (b << 8) + tid;
    if (colIdx < NN) {
        inc[colIdx] = start + scn[tid];
        dis[colIdx] = (v > 0) ? rsqrtf((float)v) : 0.f;
    }
}

// per bucket: scatter packed (src, w = dis[src]*dis[col]) into CSR order
__global__ void __launch_bounds__(256) k_bcsr_b(const int* __restrict__ bh,
                                                const int* __restrict__ ebuck,
                                                const int* __restrict__ inc,
                                                const float* __restrict__ dis,
                                                int2* __restrict__ esrc8) {
    __shared__ int cur[256];
    __shared__ float sdis[256];
    int b = blockIdx.x, tid = threadIdx.x;
    int start = (b == 0) ? 0 : bh[b * NBLK - 1];
    int end   = bh[(b + 1) * NBLK - 1];
    int colIdx = (b << 8) + tid;
    cur[tid]  = (colIdx == 0) ? 0 : ((colIdx <= NN) ? inc[colIdx - 1] : 0);
    sdis[tid] = (colIdx < NN) ? dis[colIdx] : 0.f;
    __syncthreads();
    for (int j = start + tid; j < end; j += 256) {
        int e = ebuck[j];
        int c = e & 255, s = e >> 8;
        int pos = atomicAdd(&cur[c], 1);
        float w = dis[s] * sdis[c];
        esrc8[pos] = make_int2(s, __float_as_int(w));
    }
}

// layer1 gather + relu + K-mean + dense2. 8 lanes/node, float4 rows, packed edges.
__global__ void k_gather1_mid(const int* __restrict__ inc, const int2* __restrict__ esrc8,
                              const float4* __restrict__ h1, const float4* __restrict__ r1,
                              const float4* __restrict__ Wi2, const float4* __restrict__ Wr2,
                              const float* __restrict__ b2,
                              float* __restrict__ h2, float* __restrict__ r2) {
    int tid = blockIdx.x * blockDim.x + threadIdx.x;
    int n = tid >> 3, l = tid & 7;
    if (n >= NN) return;
    int js = (n == 0) ? 0 : inc[n - 1];
    int je = inc[n];
    float4 acc = r1[(size_t)n * 8 + l];
    int j = js;
    if ((j & 1) && j < je) {
        int2 e = esrc8[j];
        float w = __int_as_float(e.y);
        float4 v = h1[(size_t)e.x * 8 + l];
        acc.x = fmaf(w, v.x, acc.x); acc.y = fmaf(w, v.y, acc.y);
        acc.z = fmaf(w, v.z, acc.z); acc.w = fmaf(w, v.w, acc.w);
        j++;
    }
    for (; j + 1 < je; j += 2) {
        int4 ep = *(const int4*)&esrc8[j];
        float w0 = __int_as_float(ep.y), w1 = __int_as_float(ep.w);
        float4 v0 = h1[(size_t)ep.x * 8 + l];
        float4 v1 = h1[(size_t)ep.z * 8 + l];
        acc.x = fmaf(w0, v0.x, acc.x); acc.y = fmaf(w0, v0.y, acc.y);
        acc.z = fmaf(w0, v0.z, acc.z); acc.w = fmaf(w0, v0.w, acc.w);
        acc.x = fmaf(w1, v1.x, acc.x); acc.y = fmaf(w1, v1.y, acc.y);
        acc.z = fmaf(w1, v1.z, acc.z); acc.w = fmaf(w1, v1.w, acc.w);
    }
    if (j < je) {
        int2 e = esrc8[j];
        float w = __int_as_float(e.y);
        float4 v = h1[(size_t)e.x * 8 + l];
        acc.x = fmaf(w, v.x, acc.x); acc.y = fmaf(w, v.y, acc.y);
        acc.z = fmaf(w, v.z, acc.z); acc.w = fmaf(w, v.w, acc.w);
    }
    acc.x = fmaxf(acc.x, 0.f); acc.y = fmaxf(acc.y, 0.f);
    acc.z = fmaxf(acc.z, 0.f); acc.w = fmaxf(acc.w, 0.f);
    float4 h;
    h.x = 0.5f * (acc.x + __shfl_xor(acc.x, 4));
    h.y = 0.5f * (acc.y + __shfl_xor(acc.y, 4));
    h.z = 0.5f * (acc.z + __shfl_xor(acc.z, 4));
    h.w = 0.5f * (acc.w + __shfl_xor(acc.w, 4));
    float4 wi = Wi2[l], wr = Wr2[l];
    float p1 = h.x * wi.x + h.y * wi.y + h.z * wi.z + h.w * wi.w;
    float p2 = h.x * wr.x + h.y * wr.y + h.z * wr.z + h.w * wr.w;
    p1 += __shfl_xor(p1, 1); p1 += __shfl_xor(p1, 2);
    p2 += __shfl_xor(p2, 1); p2 += __shfl_xor(p2, 2);
    if ((l & 3) == 0) {
        int k = l >> 2;
        h2[n * 2 + k] = p1;
        r2[n * 2 + k] = p2 + b2[k];
    }
}

// layer2 gather: 8 lanes/node, edge-parallel over packed pairs
__global__ void k_gather2(const int* __restrict__ inc, const int2* __restrict__ esrc8,
                          const float* __restrict__ h2, const float* __restrict__ r2,
                          float* __restrict__ out) {
    int tid = blockIdx.x * blockDim.x + threadIdx.x;
    int n = tid >> 3, l = tid & 7;
    if (n >= NN) return;
    int js = (n == 0) ? 0 : inc[n - 1];
    int je = inc[n];
    float a0 = 0.f, a1v = 0.f;
    for (int j = js + l; j < je; j += 8) {
        int2 e = esrc8[j];
        float w = __int_as_float(e.y);
        float2 hv = *(const float2*)&h2[(size_t)e.x * 2];
        a0  = fmaf(w, hv.x, a0);
        a1v = fmaf(w, hv.y, a1v);
    }
    a0  += __shfl_xor(a0, 1);  a0  += __shfl_xor(a0, 2);  a0  += __shfl_xor(a0, 4);
    a1v += __shfl_xor(a1v, 1); a1v += __shfl_xor(a1v, 2); a1v += __shfl_xor(a1v, 4);
    if (l == 0) {
        float2 rv = *(const float2*)&r2[(size_t)n * 2];
        out[n] = 0.5f * (fmaxf(a0 + rv.x, 0.f) + fmaxf(a1v + rv.y, 0.f));
    }
}

extern "C" void kernel_launch(void* const* d_in, const int* in_sizes, int n_in,
                              void* d_out, int out_size, void* d_ws, size_t ws_size,
                              hipStream_t stream) {
    const float* x   = (const float*)d_in[0];
    const int*   ei  = (const int*)d_in[1];
    const float* Wi1 = (const float*)d_in[2];
    const float* Wr1 = (const float*)d_in[3];
    const float* b1  = (const float*)d_in[4];
    const float* Wi2 = (const float*)d_in[5];
    const float* Wr2 = (const float*)d_in[6];
    const float* b2  = (const float*)d_in[7];
    float* out = (float*)d_out;

    const int* row = ei;
    const int* col = ei + NE;

    int*   bh    = (int*)d_ws;                       // 100096
    int*   bsum  = bh + SCANN;                       // 128
    int*   boff  = bsum + 128;                       // 128
    float* dis   = (float*)(boff + 128);             // NN
    int*   inc   = (int*)(dis + NN);                 // NN
    int*   ebuck = inc + NN;                         // NE
    int2*  esrc8 = (int2*)(ebuck + NE);              // NE int2 (16B-aligned)
    float* h1    = (float*)(esrc8 + NE);             // NN*32
    float* r1    = h1 + (size_t)NN * FH2;            // NN*32
    float* h2    = r1 + (size_t)NN * FH2;            // NN*2
    float* r2    = h2 + (size_t)NN * KS;             // NN*2

    const int B = 256;
    k_hist_dense1<<<NBLK + DENSE_BLOCKS, B, 0, stream>>>(col, bh, x, Wi1, Wr1, b1, h1, r1);
    k_scan1<<<SCAN_BLOCKS, B, 0, stream>>>(bh, bsum);
    k_scan2<<<1, 128, 0, stream>>>(bsum, boff);
    k_scan3<<<(SCANN + B - 1) / B, B, 0, stream>>>(bh, boff);
    k_bscatter<<<NBLK, B, 0, stream>>>(row, col, bh, ebuck);
    k_bcsr_a<<<NB, B, 0, stream>>>(bh, ebuck, inc, dis);
    k_bcsr_b<<<NB, B, 0, stream>>>(bh, ebuck, inc, dis, esrc8);
    k_gather1_mid<<<(NN * 8 + B - 1) / B, B, 0, stream>>>(inc, esrc8,
        (const float4*)h1, (const float4*)r1, (const float4*)Wi2, (const float4*)Wr2,
        b2, h2, r2);
    k_gather2<<<(NN * 8 + B - 1) / B, B, 0, stream>>>(inc, esrc8, h2, r2, out);
}

// Round 13
// 129.328 us; speedup vs baseline: 5.4618x; 1.0911x over previous
//
#include <hip/hip_runtime.h>

#define NN 100000
#define NE 1600000

constexpr int F_IN = 58;
constexpr int FH2  = 32;            // KS * F_H
constexpr int KS   = 2;

constexpr int NB   = 391;           // buckets: col >> 8
constexpr int NBLK = 256;           // partition blocks
constexpr int EPB  = NE / NBLK;     // 6250
constexpr int SCANN = NB * NBLK;    // 100096
constexpr int SCAN_BLOCKS = (SCANN + 1023) / 1024;  // 98
constexpr int DN_NODES = 64;        // dense1 nodes per block (MFMA 4 M-tiles)
constexpr int DENSE_BLOCKS = (NN + DN_NODES - 1) / DN_NODES;  // 1563

using short8 = __attribute__((ext_vector_type(8))) short;
using f32x4  = __attribute__((ext_vector_type(4))) float;

// f32 -> (bf16 hi, bf16 lo) by truncation; hi+lo rel err ~2^-16
__device__ inline void splitbf(float v, short& hi, short& lo) {
    unsigned ub = __float_as_uint(v);
    unsigned short h = (unsigned short)(ub >> 16);
    float hif = __uint_as_float(((unsigned)h) << 16);
    float lof = v - hif;
    unsigned short l = (unsigned short)(__float_as_uint(lof) >> 16);
    hi = (short)h; lo = (short)l;
}

// blocks [0,NBLK): per-block bucket histogram (single-copy LDS atomics).
// blocks [NBLK,...): dense layer-1 via split-precision bf16 MFMA:
//   h = x_hi@W_h + x_hi@W_l + x_lo@W_h  (error ~2^-16, f32-equivalent).
//   A[64 nodes][128 k] = [x_hi(58)+pad | x_lo(58)+pad], B^T[64 cols][128 k],
//   both XOR-swizzled (byte ^= (row&7)<<4) per G4 for conflict-free b128.
__global__ void k_hist_dense1(const int* __restrict__ col, int* __restrict__ bh,
                              const float* __restrict__ x,
                              const float* __restrict__ Wi, const float* __restrict__ Wr,
                              const float* __restrict__ b,
                              float* __restrict__ h1, float* __restrict__ r1) {
    __shared__ int hist[NB];
    __shared__ short sA[64 * 128];   // 16 KB
    __shared__ short sB[64 * 128];   // 16 KB
    int tid = threadIdx.x;

    if (blockIdx.x < NBLK) {
        int blk = blockIdx.x;
        for (int i = tid; i < NB; i += 256) hist[i] = 0;
        __syncthreads();
        int base = blk * EPB;
        for (int e = base + tid; e < base + EPB; e += 256)
            atomicAdd(&hist[col[e] >> 8], 1);
        __syncthreads();
        for (int i = tid; i < NB; i += 256)
            bh[i * NBLK + blk] = hist[i];
        return;
    }

    int nodeBase = (blockIdx.x - NBLK) * DN_NODES;
    // ---- stage A: x rows -> bf16 hi/lo, swizzled ----
    for (int t = tid; t < 64 * F_IN; t += 256) {
        int rowl = t / F_IN, cc = t - rowl * F_IN;
        int n = nodeBase + rowl;
        float v = (n < NN) ? x[(size_t)n * F_IN + cc] : 0.f;
        short hi, lo; splitbf(v, hi, lo);
        int base = rowl * 256, xr = (rowl & 7) << 4;
        *(short*)((char*)sA + ((base + cc * 2) ^ xr)) = hi;
        *(short*)((char*)sA + ((base + (64 + cc) * 2) ^ xr)) = lo;
    }
    for (int t = tid; t < 64 * 6; t += 256) {      // zero-pad k 58..63 both halves
        int rowl = t / 6, cc = 58 + (t - (t / 6) * 6);
        int base = rowl * 256, xr = (rowl & 7) << 4;
        *(short*)((char*)sA + ((base + cc * 2) ^ xr)) = 0;
        *(short*)((char*)sA + ((base + (64 + cc) * 2) ^ xr)) = 0;
    }
    // ---- stage B^T: cols 0-31 = Wi[ko], 32-63 = Wr[ko]; k-halves = W_h | W_l ----
    for (int t = tid; t < 64 * F_IN; t += 256) {
        int colc = t / F_IN, i = t - colc * F_IN;
        int ko = colc & 31, kst = ko >> 4, o = ko & 15;
        const float* W = (colc < 32) ? Wi : Wr;
        float v = W[(kst * F_IN + i) * 16 + o];
        short hi, lo; splitbf(v, hi, lo);
        int base = colc * 256, xr = (colc & 7) << 4;
        *(short*)((char*)sB + ((base + i * 2) ^ xr)) = hi;
        *(short*)((char*)sB + ((base + (64 + i) * 2) ^ xr)) = lo;
    }
    for (int t = tid; t < 64 * 6; t += 256) {
        int colc = t / 6, cc = 58 + (t - (t / 6) * 6);
        int base = colc * 256, xr = (colc & 7) << 4;
        *(short*)((char*)sB + ((base + cc * 2) ^ xr)) = 0;
        *(short*)((char*)sB + ((base + (64 + cc) * 2) ^ xr)) = 0;
    }
    __syncthreads();

    int lane = tid & 63, w = tid >> 6;   // w = M-tile (16 nodes)
    int r15 = lane & 15, h4 = lane >> 4;
    int arow = w * 16 + r15;
    int abase = arow * 256, axr = (arow & 7) << 4;
    f32x4 acc0 = {0,0,0,0}, acc1 = {0,0,0,0}, acc2 = {0,0,0,0}, acc3 = {0,0,0,0};
    // term steps: (A-k, B-k): hi@Wh, hi@Wl, lo@Wh  (2 K-steps of 32 each)
    const int kaA[6] = {0, 32, 0, 32, 64, 96};
    const int kaB[6] = {0, 32, 64, 96, 0, 32};
#pragma unroll
    for (int s = 0; s < 6; s++) {
        int ka = kaA[s], kb = kaB[s];
        short8 af = *(const short8*)((const char*)sA + ((abase + (ka + h4 * 8) * 2) ^ axr));
#define BMM(nt, accv) { \
        int bcol = nt * 16 + r15; \
        short8 bf = *(const short8*)((const char*)sB + \
            ((bcol * 256 + (kb + h4 * 8) * 2) ^ ((bcol & 7) << 4))); \
        accv = __builtin_amdgcn_mfma_f32_16x16x32_bf16(af, bf, accv, 0, 0, 0); }
        BMM(0, acc0) BMM(1, acc1) BMM(2, acc2) BMM(3, acc3)
#undef BMM
    }
    // epilogue: D map col=lane&15, row=(lane>>4)*4+reg (verified m89)
    int nb0 = nodeBase + w * 16 + h4 * 4;
#define WH(nt, accv) { int colg = nt * 16 + r15; \
    if (nb0 + 0 < NN) h1[(size_t)(nb0 + 0) * 32 + colg] = accv[0]; \
    if (nb0 + 1 < NN) h1[(size_t)(nb0 + 1) * 32 + colg] = accv[1]; \
    if (nb0 + 2 < NN) h1[(size_t)(nb0 + 2) * 32 + colg] = accv[2]; \
    if (nb0 + 3 < NN) h1[(size_t)(nb0 + 3) * 32 + colg] = accv[3]; }
#define WR(nt, accv) { int colg = nt * 16 + r15 - 32; float bv = b[colg]; \
    if (nb0 + 0 < NN) r1[(size_t)(nb0 + 0) * 32 + colg] = accv[0] + bv; \
    if (nb0 + 1 < NN) r1[(size_t)(nb0 + 1) * 32 + colg] = accv[1] + bv; \
    if (nb0 + 2 < NN) r1[(size_t)(nb0 + 2) * 32 + colg] = accv[2] + bv; \
    if (nb0 + 3 < NN) r1[(size_t)(nb0 + 3) * 32 + colg] = accv[3] + bv; }
    WH(0, acc0) WH(1, acc1) WR(2, acc2) WR(3, acc3)
#undef WH
#undef WR
}

__global__ void k_scan1(int* __restrict__ bh, int* __restrict__ bsum) {
    __shared__ int ts[256];
    int tid = threadIdx.x;
    int base = blockIdx.x * 1024 + tid * 4;
    int v0 = (base + 0 < SCANN) ? bh[base + 0] : 0;
    int v1 = (base + 1 < SCANN) ? bh[base + 1] : 0;
    int v2 = (base + 2 < SCANN) ? bh[base + 2] : 0;
    int v3 = (base + 3 < SCANN) ? bh[base + 3] : 0;
    int p0 = v0, p1 = p0 + v1, p2 = p1 + v2, p3 = p2 + v3;
    ts[tid] = p3;
    __syncthreads();
    for (int off = 1; off < 256; off <<= 1) {
        int v = (tid >= off) ? ts[tid - off] : 0;
        __syncthreads();
        ts[tid] += v;
        __syncthreads();
    }
    int prev = (tid > 0) ? ts[tid - 1] : 0;
    if (base + 0 < SCANN) bh[base + 0] = prev + p0;
    if (base + 1 < SCANN) bh[base + 1] = prev + p1;
    if (base + 2 < SCANN) bh[base + 2] = prev + p2;
    if (base + 3 < SCANN) bh[base + 3] = prev + p3;
    if (tid == 255) bsum[blockIdx.x] = ts[255];
}

__global__ void k_scan2(const int* __restrict__ bsum, int* __restrict__ boff) {
    __shared__ int s[128];
    int tid = threadIdx.x;
    s[tid] = (tid < SCAN_BLOCKS) ? bsum[tid] : 0;
    __syncthreads();
    for (int off = 1; off < 128; off <<= 1) {
        int v = (tid >= off) ? s[tid - off] : 0;
        __syncthreads();
        s[tid] += v;
        __syncthreads();
    }
    if (tid < SCAN_BLOCKS) boff[tid] = (tid > 0) ? s[tid - 1] : 0;
}

__global__ void k_scan3(int* __restrict__ bh, const int* __restrict__ boff) {
    int i = blockIdx.x * blockDim.x + threadIdx.x;
    if (i < SCANN) bh[i] += boff[i >> 10];
}

__global__ void k_bscatter(const int* __restrict__ row, const int* __restrict__ col,
                           const int* __restrict__ bh, int* __restrict__ ebuck) {
    __shared__ int cur[NB];
    int tid = threadIdx.x, blk = blockIdx.x;
    for (int i = tid; i < NB; i += 256) {
        int idx = i * NBLK + blk;
        cur[i] = (idx == 0) ? 0 : bh[idx - 1];
    }
    __syncthreads();
    int base = blk * EPB;
    for (int e = base + tid; e < base + EPB; e += 256) {
        int c = col[e];
        int pos = atomicAdd(&cur[c >> 8], 1);
        ebuck[pos] = (row[e] << 8) | (c & 255);
    }
}

// per bucket: per-col counts (2-way replicated) + scan -> inc, dis
__global__ void __launch_bounds__(256) k_bcsr_a(const int* __restrict__ bh,
                                                const int* __restrict__ ebuck,
                                                int* __restrict__ inc, float* __restrict__ dis) {
    __shared__ int cnt[514];
    __shared__ int scn[256];
    int b = blockIdx.x, tid = threadIdx.x;
    int start = (b == 0) ? 0 : bh[b * NBLK - 1];
    int end   = bh[(b + 1) * NBLK - 1];
    cnt[tid] = 0; cnt[257 + tid] = 0;
    __syncthreads();
    int c0 = (tid & 1) * 257;
    for (int j = start + tid; j < end; j += 256)
        atomicAdd(&cnt[c0 + (ebuck[j] & 255)], 1);
    __syncthreads();
    int v = cnt[tid] + cnt[257 + tid];
    scn[tid] = v;
    __syncthreads();
    for (int off = 1; off < 256; off <<= 1) {
        int t = (tid >= off) ? scn[tid - off] : 0;
        __syncthreads();
        scn[tid] += t;
        __syncthreads();
    }
    int colIdx = (b << 8) + tid;
    if (colIdx < NN) {
        inc[colIdx] = start + scn[tid];
        dis[colIdx] = (v > 0) ? rsqrtf((float)v) : 0.f;
    }
}

// per bucket: scatter packed (src, w = dis[src]*dis[col]) into CSR order
__global__ void __launch_bounds__(256) k_bcsr_b(const int* __restrict__ bh,
                                                const int* __restrict__ ebuck,
                                                const int* __restrict__ inc,
                                                const float* __restrict__ dis,
                                                int2* __restrict__ esrc8) {
    __shared__ int cur[256];
    __shared__ float sdis[256];
    int b = blockIdx.x, tid = threadIdx.x;
    int start = (b == 0) ? 0 : bh[b * NBLK - 1];
    int end   = bh[(b + 1) * NBLK - 1];
    int colIdx = (b << 8) + tid;
    cur[tid]  = (colIdx == 0) ? 0 : ((colIdx <= NN) ? inc[colIdx - 1] : 0);
    sdis[tid] = (colIdx < NN) ? dis[colIdx] : 0.f;
    __syncthreads();
    for (int j = start + tid; j < end; j += 256) {
        int e = ebuck[j];
        int c = e & 255, s = e >> 8;
        int pos = atomicAdd(&cur[c], 1);
        float w = dis[s] * sdis[c];
        esrc8[pos] = make_int2(s, __float_as_int(w));
    }
}

// layer1 gather + relu + K-mean + dense2. 8 lanes/node, float4 rows, packed edges.
__global__ void k_gather1_mid(const int* __restrict__ inc, const int2* __restrict__ esrc8,
                              const float4* __restrict__ h1, const float4* __restrict__ r1,
                              const float4* __restrict__ Wi2, const float4* __restrict__ Wr2,
                              const float* __restrict__ b2,
                              float* __restrict__ h2, float* __restrict__ r2) {
    int tid = blockIdx.x * blockDim.x + threadIdx.x;
    int n = tid >> 3, l = tid & 7;
    if (n >= NN) return;
    int js = (n == 0) ? 0 : inc[n - 1];
    int je = inc[n];
    float4 acc = r1[(size_t)n * 8 + l];
    int j = js;
    if ((j & 1) && j < je) {
        int2 e = esrc8[j];
        float w = __int_as_float(e.y);
        float4 v = h1[(size_t)e.x * 8 + l];
        acc.x = fmaf(w, v.x, acc.x); acc.y = fmaf(w, v.y, acc.y);
        acc.z = fmaf(w, v.z, acc.z); acc.w = fmaf(w, v.w, acc.w);
        j++;
    }
    for (; j + 1 < je; j += 2) {
        int4 ep = *(const int4*)&esrc8[j];
        float w0 = __int_as_float(ep.y), w1 = __int_as_float(ep.w);
        float4 v0 = h1[(size_t)ep.x * 8 + l];
        float4 v1 = h1[(size_t)ep.z * 8 + l];
        acc.x = fmaf(w0, v0.x, acc.x); acc.y = fmaf(w0, v0.y, acc.y);
        acc.z = fmaf(w0, v0.z, acc.z); acc.w = fmaf(w0, v0.w, acc.w);
        acc.x = fmaf(w1, v1.x, acc.x); acc.y = fmaf(w1, v1.y, acc.y);
        acc.z = fmaf(w1, v1.z, acc.z); acc.w = fmaf(w1, v1.w, acc.w);
    }
    if (j < je) {
        int2 e = esrc8[j];
        float w = __int_as_float(e.y);
        float4 v = h1[(size_t)e.x * 8 + l];
        acc.x = fmaf(w, v.x, acc.x); acc.y = fmaf(w, v.y, acc.y);
        acc.z = fmaf(w, v.z, acc.z); acc.w = fmaf(w, v.w, acc.w);
    }
    acc.x = fmaxf(acc.x, 0.f); acc.y = fmaxf(acc.y, 0.f);
    acc.z = fmaxf(acc.z, 0.f); acc.w = fmaxf(acc.w, 0.f);
    float4 h;
    h.x = 0.5f * (acc.x + __shfl_xor(acc.x, 4));
    h.y = 0.5f * (acc.y + __shfl_xor(acc.y, 4));
    h.z = 0.5f * (acc.z + __shfl_xor(acc.z, 4));
    h.w = 0.5f * (acc.w + __shfl_xor(acc.w, 4));
    float4 wi = Wi2[l], wr = Wr2[l];
    float p1 = h.x * wi.x + h.y * wi.y + h.z * wi.z + h.w * wi.w;
    float p2 = h.x * wr.x + h.y * wr.y + h.z * wr.z + h.w * wr.w;
    p1 += __shfl_xor(p1, 1); p1 += __shfl_xor(p1, 2);
    p2 += __shfl_xor(p2, 1); p2 += __shfl_xor(p2, 2);
    if ((l & 3) == 0) {
        int k = l >> 2;
        h2[n * 2 + k] = p1;
        r2[n * 2 + k] = p2 + b2[k];
    }
}

// layer2 gather: 8 lanes/node, edge-parallel over packed pairs
__global__ void k_gather2(const int* __restrict__ inc, const int2* __restrict__ esrc8,
                          const float* __restrict__ h2, const float* __restrict__ r2,
                          float* __restrict__ out) {
    int tid = blockIdx.x * blockDim.x + threadIdx.x;
    int n = tid >> 3, l = tid & 7;
    if (n >= NN) return;
    int js = (n == 0) ? 0 : inc[n - 1];
    int je = inc[n];
    float a0 = 0.f, a1v = 0.f;
    for (int j = js + l; j < je; j += 8) {
        int2 e = esrc8[j];
        float w = __int_as_float(e.y);
        float2 hv = *(const float2*)&h2[(size_t)e.x * 2];
        a0  = fmaf(w, hv.x, a0);
        a1v = fmaf(w, hv.y, a1v);
    }
    a0  += __shfl_xor(a0, 1);  a0  += __shfl_xor(a0, 2);  a0  += __shfl_xor(a0, 4);
    a1v += __shfl_xor(a1v, 1); a1v += __shfl_xor(a1v, 2); a1v += __shfl_xor(a1v, 4);
    if (l == 0) {
        float2 rv = *(const float2*)&r2[(size_t)n * 2];
        out[n] = 0.5f * (fmaxf(a0 + rv.x, 0.f) + fmaxf(a1v + rv.y, 0.f));
    }
}

extern "C" void kernel_launch(void* const* d_in, const int* in_sizes, int n_in,
                              void* d_out, int out_size, void* d_ws, size_t ws_size,
                              hipStream_t stream) {
    const float* x   = (const float*)d_in[0];
    const int*   ei  = (const int*)d_in[1];
    const float* Wi1 = (const float*)d_in[2];
    const float* Wr1 = (const float*)d_in[3];
    const float* b1  = (const float*)d_in[4];
    const float* Wi2 = (const float*)d_in[5];
    const float* Wr2 = (const float*)d_in[6];
    const float* b2  = (const float*)d_in[7];
    float* out = (float*)d_out;

    const int* row = ei;
    const int* col = ei + NE;

    int*   bh    = (int*)d_ws;                       // 100096
    int*   bsum  = bh + SCANN;                       // 128
    int*   boff  = bsum + 128;                       // 128
    float* dis   = (float*)(boff + 128);             // NN
    int*   inc   = (int*)(dis + NN);                 // NN
    int*   ebuck = inc + NN;                         // NE
    int2*  esrc8 = (int2*)(ebuck + NE);              // NE int2 (16B-aligned)
    float* h1    = (float*)(esrc8 + NE);             // NN*32
    float* r1    = h1 + (size_t)NN * FH2;            // NN*32
    float* h2    = r1 + (size_t)NN * FH2;            // NN*2
    float* r2    = h2 + (size_t)NN * KS;             // NN*2

    const int B = 256;
    k_hist_dense1<<<NBLK + DENSE_BLOCKS, B, 0, stream>>>(col, bh, x, Wi1, Wr1, b1, h1, r1);
    k_scan1<<<SCAN_BLOCKS, B, 0, stream>>>(bh, bsum);
    k_scan2<<<1, 128, 0, stream>>>(bsum, boff);
    k_scan3<<<(SCANN + B - 1) / B, B, 0, stream>>>(bh, boff);
    k_bscatter<<<NBLK, B, 0, stream>>>(row, col, bh, ebuck);
    k_bcsr_a<<<NB, B, 0, stream>>>(bh, ebuck, inc, dis);
    k_bcsr_b<<<NB, B, 0, stream>>>(bh, ebuck, inc, dis, esrc8);
    k_gather1_mid<<<(NN * 8 + B - 1) / B, B, 0, stream>>>(inc, esrc8,
        (const float4*)h1, (const float4*)r1, (const float4*)Wi2, (const float4*)Wr2,
        b2, h2, r2);
    k_gather2<<<(NN * 8 + B - 1) / B, B, 0, stream>>>(inc, esrc8, h2, r2, out);
}

// Round 14
// 111.592 us; speedup vs baseline: 6.3299x; 1.1589x over previous
//
#include <hip/hip_runtime.h>

#define NN 100000
#define NE 1600000

constexpr int F_IN = 58;
constexpr int FH2  = 32;            // KS * F_H
constexpr int KS   = 2;

constexpr int NB   = 391;           // buckets: col >> 8
constexpr int NBLK = 256;           // partition blocks
constexpr int EPB  = NE / NBLK;     // 6250 (even; base byte offset 25000*blk is 8B-aligned)
constexpr int SCANN = NB * NBLK;    // 100096
constexpr int SCAN_BLOCKS = (SCANN + 1023) / 1024;  // 98
constexpr int DN_NODES = 64;
constexpr int DENSE_BLOCKS = (NN + DN_NODES - 1) / DN_NODES;  // 1563
constexpr int LROW = 136;           // padded LDS row stride in shorts (272 B)

using short8 = __attribute__((ext_vector_type(8))) short;
using f32x4  = __attribute__((ext_vector_type(4))) float;

// f32 -> (bf16 hi, bf16 lo) by truncation; hi+lo rel err ~2^-16
__device__ inline void splitbf(float v, short& hi, short& lo) {
    unsigned ub = __float_as_uint(v);
    unsigned short h = (unsigned short)(ub >> 16);
    float hif = __uint_as_float(((unsigned)h) << 16);
    float lof = v - hif;
    unsigned short l = (unsigned short)(__float_as_uint(lof) >> 16);
    hi = (short)h; lo = (short)l;
}

// one-time weight split: wpre[c*128 + kk]; c = 0..31 Wi[ko=c], 32..63 Wr[ko=c-32];
// kk 0..63 = hi of W element i=kk (i<58 else 0), kk 64..127 = lo.
__global__ void k_prep_w(const float* __restrict__ Wi, const float* __restrict__ Wr,
                         short* __restrict__ wpre) {
    int t = threadIdx.x;
    for (int idx = t; idx < 64 * 64; idx += 256) {
        int c = idx >> 6, i = idx & 63;
        int ko = c & 31, kst = ko >> 4, o = ko & 15;
        const float* W = (c < 32) ? Wi : Wr;
        float v = (i < F_IN) ? W[(kst * F_IN + i) * 16 + o] : 0.f;
        short hi, lo; splitbf(v, hi, lo);
        wpre[c * 128 + i] = hi;
        wpre[c * 128 + 64 + i] = lo;
    }
}

// blocks [0,NBLK): per-block bucket histogram (single-copy LDS atomics, int2 loads).
// blocks [NBLK,...): dense layer-1 via split-bf16 MFMA, PADDED LDS (no XOR):
//   row stride 136 shorts -> reads and writes <=2-way bank alias (free).
__global__ void k_hist_dense1(const int* __restrict__ col, int* __restrict__ bh,
                              const float* __restrict__ x,
                              const short* __restrict__ wpre,
                              const float* __restrict__ b,
                              float* __restrict__ h1, float* __restrict__ r1) {
    __shared__ int hist[NB];
    __shared__ short sA[64 * LROW];   // 17 KB
    __shared__ short sB[64 * LROW];   // 17 KB
    int tid = threadIdx.x;

    if (blockIdx.x < NBLK) {
        int blk = blockIdx.x;
        for (int i = tid; i < NB; i += 256) hist[i] = 0;
        __syncthreads();
        const int2* c2p = (const int2*)&col[blk * EPB];
        for (int c = tid; c < EPB / 2; c += 256) {
            int2 cc = c2p[c];
            atomicAdd(&hist[cc.x >> 8], 1);
            atomicAdd(&hist[cc.y >> 8], 1);
        }
        __syncthreads();
        for (int i = tid; i < NB; i += 256)
            bh[i * NBLK + blk] = hist[i];
        return;
    }

    int nodeBase = (blockIdx.x - NBLK) * DN_NODES;
    // stage B: copy pre-split weights, 16B chunks (coalesced read, 2-way LDS write)
    for (int t = tid; t < 1024; t += 256) {
        int c = t >> 4, q8 = t & 15;
        *(short8*)&sB[c * LROW + q8 * 8] = *(const short8*)&wpre[c * 128 + q8 * 8];
    }
    // stage A: x rows -> hi/lo bf16, short4 writes
    for (int t = tid; t < 1024; t += 256) {
        int r = t >> 4, q4 = t & 15;
        int n = nodeBase + r;
        float v0 = 0.f, v1 = 0.f, v2 = 0.f, v3 = 0.f;
        int i0 = q4 * 4;
        if (n < NN && i0 < F_IN) {
            float2 a = *(const float2*)&x[(size_t)n * F_IN + i0];   // 8B-aligned
            v0 = a.x; v1 = a.y;
            if (i0 + 2 < F_IN) {
                float2 c2 = *(const float2*)&x[(size_t)n * F_IN + i0 + 2];
                v2 = c2.x; v3 = c2.y;
            }
        }
        short h0, l0, h1s, l1s, h2s, l2s, h3s, l3s;
        splitbf(v0, h0, l0); splitbf(v1, h1s, l1s);
        splitbf(v2, h2s, l2s); splitbf(v3, h3s, l3s);
        *(short4*)&sA[r * LROW + q4 * 4]      = make_short4(h0, h1s, h2s, h3s);
        *(short4*)&sA[r * LROW + 64 + q4 * 4] = make_short4(l0, l1s, l2s, l3s);
    }
    __syncthreads();

    int lane = tid & 63, w = tid >> 6;
    int r15 = lane & 15, h4 = lane >> 4;
    const short* aB = &sA[(w * 16 + r15) * LROW];
    f32x4 acc0 = {0,0,0,0}, acc1 = {0,0,0,0}, acc2 = {0,0,0,0}, acc3 = {0,0,0,0};
    // terms: hi@Wh (2 K-steps), hi@Wl, lo@Wh
    const int kaA[6] = {0, 32, 0, 32, 64, 96};
    const int kaB[6] = {0, 32, 64, 96, 0, 32};
#pragma unroll
    for (int s = 0; s < 6; s++) {
        short8 af = *(const short8*)&aB[kaA[s] + h4 * 8];
#define BMM(nt, accv) { \
        short8 bf = *(const short8*)&sB[(nt * 16 + r15) * LROW + kaB[s] + h4 * 8]; \
        accv = __builtin_amdgcn_mfma_f32_16x16x32_bf16(af, bf, accv, 0, 0, 0); }
        BMM(0, acc0) BMM(1, acc1) BMM(2, acc2) BMM(3, acc3)
#undef BMM
    }
    // D map: col=lane&15, row=(lane>>4)*4+reg (verified m89)
    int nb0 = nodeBase + w * 16 + h4 * 4;
#define WH(nt, accv) { int colg = nt * 16 + r15; \
    if (nb0 + 0 < NN) h1[(size_t)(nb0 + 0) * 32 + colg] = accv[0]; \
    if (nb0 + 1 < NN) h1[(size_t)(nb0 + 1) * 32 + colg] = accv[1]; \
    if (nb0 + 2 < NN) h1[(size_t)(nb0 + 2) * 32 + colg] = accv[2]; \
    if (nb0 + 3 < NN) h1[(size_t)(nb0 + 3) * 32 + colg] = accv[3]; }
#define WR(nt, accv) { int colg = nt * 16 + r15 - 32; float bv = b[colg]; \
    if (nb0 + 0 < NN) r1[(size_t)(nb0 + 0) * 32 + colg] = accv[0] + bv; \
    if (nb0 + 1 < NN) r1[(size_t)(nb0 + 1) * 32 + colg] = accv[1] + bv; \
    if (nb0 + 2 < NN) r1[(size_t)(nb0 + 2) * 32 + colg] = accv[2] + bv; \
    if (nb0 + 3 < NN) r1[(size_t)(nb0 + 3) * 32 + colg] = accv[3] + bv; }
    WH(0, acc0) WH(1, acc1) WR(2, acc2) WR(3, acc3)
#undef WH
#undef WR
}

__global__ void k_scan1(int* __restrict__ bh, int* __restrict__ bsum) {
    __shared__ int ts[256];
    int tid = threadIdx.x;
    int base = blockIdx.x * 1024 + tid * 4;
    int v0 = (base + 0 < SCANN) ? bh[base + 0] : 0;
    int v1 = (base + 1 < SCANN) ? bh[base + 1] : 0;
    int v2 = (base + 2 < SCANN) ? bh[base + 2] : 0;
    int v3 = (base + 3 < SCANN) ? bh[base + 3] : 0;
    int p0 = v0, p1 = p0 + v1, p2 = p1 + v2, p3 = p2 + v3;
    ts[tid] = p3;
    __syncthreads();
    for (int off = 1; off < 256; off <<= 1) {
        int v = (tid >= off) ? ts[tid - off] : 0;
        __syncthreads();
        ts[tid] += v;
        __syncthreads();
    }
    int prev = (tid > 0) ? ts[tid - 1] : 0;
    if (base + 0 < SCANN) bh[base + 0] = prev + p0;
    if (base + 1 < SCANN) bh[base + 1] = prev + p1;
    if (base + 2 < SCANN) bh[base + 2] = prev + p2;
    if (base + 3 < SCANN) bh[base + 3] = prev + p3;
    if (tid == 255) bsum[blockIdx.x] = ts[255];
}

__global__ void k_scan2(const int* __restrict__ bsum, int* __restrict__ boff) {
    __shared__ int s[128];
    int tid = threadIdx.x;
    s[tid] = (tid < SCAN_BLOCKS) ? bsum[tid] : 0;
    __syncthreads();
    for (int off = 1; off < 128; off <<= 1) {
        int v = (tid >= off) ? s[tid - off] : 0;
        __syncthreads();
        s[tid] += v;
        __syncthreads();
    }
    if (tid < SCAN_BLOCKS) boff[tid] = (tid > 0) ? s[tid - 1] : 0;
}

// scatter to bucket-major; boff applied inline (scan3 eliminated); int2 loads
__global__ void k_bscatter(const int* __restrict__ row, const int* __restrict__ col,
                           const int* __restrict__ bh, const int* __restrict__ boff,
                           int* __restrict__ ebuck) {
    __shared__ int cur[NB];
    int tid = threadIdx.x, blk = blockIdx.x;
    for (int i = tid; i < NB; i += 256) {
        int idx = i * NBLK + blk;
        cur[i] = (idx == 0) ? 0 : bh[idx - 1] + boff[(idx - 1) >> 10];
    }
    __syncthreads();
    int base = blk * EPB;
    const int2* c2p = (const int2*)&col[base];
    const int2* r2p = (const int2*)&row[base];
    for (int c = tid; c < EPB / 2; c += 256) {
        int2 cc = c2p[c];
        int2 rr = r2p[c];
        int p0 = atomicAdd(&cur[cc.x >> 8], 1);
        ebuck[p0] = (rr.x << 8) | (cc.x & 255);
        int p1 = atomicAdd(&cur[cc.y >> 8], 1);
        ebuck[p1] = (rr.y << 8) | (cc.y & 255);
    }
}

// per bucket: per-col counts (2-way replicated) + scan -> inc, dis
__global__ void __launch_bounds__(256) k_bcsr_a(const int* __restrict__ bh,
                                                const int* __restrict__ boff,
                                                const int* __restrict__ ebuck,
                                                int* __restrict__ inc, float* __restrict__ dis) {
    __shared__ int cnt[514];
    __shared__ int scn[256];
    int b = blockIdx.x, tid = threadIdx.x;
    int i0 = b * NBLK - 1, i1 = (b + 1) * NBLK - 1;
    int start = (b == 0) ? 0 : bh[i0] + boff[i0 >> 10];
    int end   = bh[i1] + boff[i1 >> 10];
    cnt[tid] = 0; cnt[257 + tid] = 0;
    __syncthreads();
    int c0 = (tid & 1) * 257;
    for (int j = start + tid; j < end; j += 256)
        atomicAdd(&cnt[c0 + (ebuck[j] & 255)], 1);
    __syncthreads();
    int v = cnt[tid] + cnt[257 + tid];
    scn[tid] = v;
    __syncthreads();
    for (int off = 1; off < 256; off <<= 1) {
        int t = (tid >= off) ? scn[tid - off] : 0;
        __syncthreads();
        scn[tid] += t;
        __syncthreads();
    }
    int colIdx = (b << 8) + tid;
    if (colIdx < NN) {
        inc[colIdx] = start + scn[tid];
        dis[colIdx] = (v > 0) ? rsqrtf((float)v) : 0.f;
    }
}

// per bucket: scatter packed (src, w = dis[src]*dis[col]) into CSR order
__global__ void __launch_bounds__(256) k_bcsr_b(const int* __restrict__ bh,
                                                const int* __restrict__ boff,
                                                const int* __restrict__ ebuck,
                                                const int* __restrict__ inc,
                                                const float* __restrict__ dis,
                                                int2* __restrict__ esrc8) {
    __shared__ int cur[256];
    __shared__ float sdis[256];
    int b = blockIdx.x, tid = threadIdx.x;
    int i0 = b * NBLK - 1, i1 = (b + 1) * NBLK - 1;
    int start = (b == 0) ? 0 : bh[i0] + boff[i0 >> 10];
    int end   = bh[i1] + boff[i1 >> 10];
    int colIdx = (b << 8) + tid;
    cur[tid]  = (colIdx == 0) ? 0 : ((colIdx <= NN) ? inc[colIdx - 1] : 0);
    sdis[tid] = (colIdx < NN) ? dis[colIdx] : 0.f;
    __syncthreads();
    for (int j = start + tid; j < end; j += 256) {
        int e = ebuck[j];
        int c = e & 255, s = e >> 8;
        int pos = atomicAdd(&cur[c], 1);
        float w = dis[s] * sdis[c];
        esrc8[pos] = make_int2(s, __float_as_int(w));
    }
}

// layer1 gather + relu + K-mean + dense2. 8 lanes/node, float4 rows, packed edges.
__global__ void k_gather1_mid(const int* __restrict__ inc, const int2* __restrict__ esrc8,
                              const float4* __restrict__ h1, const float4* __restrict__ r1,
                              const float4* __restrict__ Wi2, const float4* __restrict__ Wr2,
                              const float* __restrict__ b2,
                              float* __restrict__ h2, float* __restrict__ r2) {
    int tid = blockIdx.x * blockDim.x + threadIdx.x;
    int n = tid >> 3, l = tid & 7;
    if (n >= NN) return;
    int js = (n == 0) ? 0 : inc[n - 1];
    int je = inc[n];
    float4 acc = r1[(size_t)n * 8 + l];
    int j = js;
    if ((j & 1) && j < je) {
        int2 e = esrc8[j];
        float w = __int_as_float(e.y);
        float4 v = h1[(size_t)e.x * 8 + l];
        acc.x = fmaf(w, v.x, acc.x); acc.y = fmaf(w, v.y, acc.y);
        acc.z = fmaf(w, v.z, acc.z); acc.w = fmaf(w, v.w, acc.w);
        j++;
    }
    for (; j + 1 < je; j += 2) {
        int4 ep = *(const int4*)&esrc8[j];
        float w0 = __int_as_float(ep.y), w1 = __int_as_float(ep.w);
        float4 v0 = h1[(size_t)ep.x * 8 + l];
        float4 v1 = h1[(size_t)ep.z * 8 + l];
        acc.x = fmaf(w0, v0.x, acc.x); acc.y = fmaf(w0, v0.y, acc.y);
        acc.z = fmaf(w0, v0.z, acc.z); acc.w = fmaf(w0, v0.w, acc.w);
        acc.x = fmaf(w1, v1.x, acc.x); acc.y = fmaf(w1, v1.y, acc.y);
        acc.z = fmaf(w1, v1.z, acc.z); acc.w = fmaf(w1, v1.w, acc.w);
    }
    if (j < je) {
        int2 e = esrc8[j];
        float w = __int_as_float(e.y);
        float4 v = h1[(size_t)e.x * 8 + l];
        acc.x = fmaf(w, v.x, acc.x); acc.y = fmaf(w, v.y, acc.y);
        acc.z = fmaf(w, v.z, acc.z); acc.w = fmaf(w, v.w, acc.w);
    }
    acc.x = fmaxf(acc.x, 0.f); acc.y = fmaxf(acc.y, 0.f);
    acc.z = fmaxf(acc.z, 0.f); acc.w = fmaxf(acc.w, 0.f);
    float4 h;
    h.x = 0.5f * (acc.x + __shfl_xor(acc.x, 4));
    h.y = 0.5f * (acc.y + __shfl_xor(acc.y, 4));
    h.z = 0.5f * (acc.z + __shfl_xor(acc.z, 4));
    h.w = 0.5f * (acc.w + __shfl_xor(acc.w, 4));
    float4 wi = Wi2[l], wr = Wr2[l];
    float p1 = h.x * wi.x + h.y * wi.y + h.z * wi.z + h.w * wi.w;
    float p2 = h.x * wr.x + h.y * wr.y + h.z * wr.z + h.w * wr.w;
    p1 += __shfl_xor(p1, 1); p1 += __shfl_xor(p1, 2);
    p2 += __shfl_xor(p2, 1); p2 += __shfl_xor(p2, 2);
    if ((l & 3) == 0) {
        int k = l >> 2;
        h2[n * 2 + k] = p1;
        r2[n * 2 + k] = p2 + b2[k];
    }
}

// layer2 gather: 8 lanes/node, edge-parallel over packed pairs
__global__ void k_gather2(const int* __restrict__ inc, const int2* __restrict__ esrc8,
                          const float* __restrict__ h2, const float* __restrict__ r2,
                          float* __restrict__ out) {
    int tid = blockIdx.x * blockDim.x + threadIdx.x;
    int n = tid >> 3, l = tid & 7;
    if (n >= NN) return;
    int js = (n == 0) ? 0 : inc[n - 1];
    int je = inc[n];
    float a0 = 0.f, a1v = 0.f;
    for (int j = js + l; j < je; j += 8) {
        int2 e = esrc8[j];
        float w = __int_as_float(e.y);
        float2 hv = *(const float2*)&h2[(size_t)e.x * 2];
        a0  = fmaf(w, hv.x, a0);
        a1v = fmaf(w, hv.y, a1v);
    }
    a0  += __shfl_xor(a0, 1);  a0  += __shfl_xor(a0, 2);  a0  += __shfl_xor(a0, 4);
    a1v += __shfl_xor(a1v, 1); a1v += __shfl_xor(a1v, 2); a1v += __shfl_xor(a1v, 4);
    if (l == 0) {
        float2 rv = *(const float2*)&r2[(size_t)n * 2];
        out[n] = 0.5f * (fmaxf(a0 + rv.x, 0.f) + fmaxf(a1v + rv.y, 0.f));
    }
}

extern "C" void kernel_launch(void* const* d_in, const int* in_sizes, int n_in,
                              void* d_out, int out_size, void* d_ws, size_t ws_size,
                              hipStream_t stream) {
    const float* x   = (const float*)d_in[0];
    const int*   ei  = (const int*)d_in[1];
    const float* Wi1 = (const float*)d_in[2];
    const float* Wr1 = (const float*)d_in[3];
    const float* b1  = (const float*)d_in[4];
    const float* Wi2 = (const float*)d_in[5];
    const float* Wr2 = (const float*)d_in[6];
    const float* b2  = (const float*)d_in[7];
    float* out = (float*)d_out;

    const int* row = ei;
    const int* col = ei + NE;

    int*   bh    = (int*)d_ws;                       // 100096
    int*   bsum  = bh + SCANN;                       // 128
    int*   boff  = bsum + 128;                       // 128
    float* dis   = (float*)(boff + 128);             // NN
    int*   inc   = (int*)(dis + NN);                 // NN
    short* wpre  = (short*)(inc + NN);               // 8192 shorts (4096 ints)
    int*   ebuck = (int*)(wpre + 8192);              // NE
    int2*  esrc8 = (int2*)(ebuck + NE);              // NE int2 (16B-aligned)
    float* h1    = (float*)(esrc8 + NE);             // NN*32
    float* r1    = h1 + (size_t)NN * FH2;            // NN*32
    float* h2    = r1 + (size_t)NN * FH2;            // NN*2
    float* r2    = h2 + (size_t)NN * KS;             // NN*2

    const int B = 256;
    k_prep_w<<<1, B, 0, stream>>>(Wi1, Wr1, wpre);
    k_hist_dense1<<<NBLK + DENSE_BLOCKS, B, 0, stream>>>(col, bh, x, wpre, b1, h1, r1);
    k_scan1<<<SCAN_BLOCKS, B, 0, stream>>>(bh, bsum);
    k_scan2<<<1, 128, 0, stream>>>(bsum, boff);
    k_bscatter<<<NBLK, B, 0, stream>>>(row, col, bh, boff, ebuck);
    k_bcsr_a<<<NB, B, 0, stream>>>(bh, boff, ebuck, inc, dis);
    k_bcsr_b<<<NB, B, 0, stream>>>(bh, boff, ebuck, inc, dis, esrc8);
    k_gather1_mid<<<(NN * 8 + B - 1) / B, B, 0, stream>>>(inc, esrc8,
        (const float4*)h1, (const float4*)r1, (const float4*)Wi2, (const float4*)Wr2,
        b2, h2, r2);
    k_gather2<<<(NN * 8 + B - 1) / B, B, 0, stream>>>(inc, esrc8, h2, r2, out);
}